// Round 14
// baseline (627.092 us; speedup 1.0000x reference)
//
#include <hip/hip_runtime.h>
#include <hip/hip_bf16.h>

#define B_ 4
#define D_ 2048
#define HWS 64
#define C_ 192
#define G_ 128
#define NODES (B_*D_)   // 8192
#define R_ 16           // central rows per fused block
#define HALO_ROWS 48    // t0-15 .. t0+32 staged
#define NBLK 512

typedef short bf8_t  __attribute__((ext_vector_type(8)));   // 8 bf16 (4 VGPR)
typedef float f32x4_t __attribute__((ext_vector_type(4)));
typedef unsigned short us4_t __attribute__((ext_vector_type(4)));

__device__ inline unsigned short f2bf(float f) {
    unsigned int u = __builtin_bit_cast(unsigned int, f);
    unsigned int r = (u + 0x7fffu + ((u >> 16) & 1u)) >> 16;   // RNE
    return (unsigned short)r;
}
__device__ inline float bf2f(unsigned short h) {
    unsigned int u = ((unsigned int)h) << 16;
    return __builtin_bit_cast(float, u);
}

// ---- device-scope grid barrier (counters zeroed per launch) ------------
__device__ inline void gbar(unsigned* cnt, int tid)
{
    __syncthreads();
    __threadfence();                       // release: writeback to device scope
    if (tid == 0) {
        __hip_atomic_fetch_add(cnt, 1u, __ATOMIC_ACQ_REL, __HIP_MEMORY_SCOPE_AGENT);
        long it = 0;
        while (__hip_atomic_load(cnt, __ATOMIC_ACQUIRE, __HIP_MEMORY_SCOPE_AGENT) < NBLK
               && it < (1L << 22)) {
            __builtin_amdgcn_s_sleep(8);
            ++it;
        }
    }
    __syncthreads();
    __threadfence();                       // acquire: invalidate stale caches
}

// ---------------- K0: weight conversion to bf16 WT[n][k] (+root fold) ---
struct WconvArgs {
    const float* src[16];
    const float* add[16];   // null or w_root slice (folded into slot 0)
};
__global__ __launch_bounds__(256) void wconv_kernel(WconvArgs a, unsigned short* __restrict__ dst)
{
    int m = blockIdx.y;
    int idx = blockIdx.x * 256 + threadIdx.x;   // n*128 + k
    int n = idx >> 7;
    int k = idx & 127;
    float v = a.src[m][k * G_ + n];
    if (a.add[m]) v += a.add[m][k * G_ + n];
    dst[(size_t)m * 16384 + idx] = f2bf(v);
}

// ---------------- K1: spatial mean-pool + FC + LayerNorm (-> bf16) ------
// PROVEN — unchanged from r9/r11.
__global__ __launch_bounds__(192) void pool_fc_ln_kernel(
    const float* __restrict__ x, const float* __restrict__ W,
    const float* __restrict__ bias, const float* __restrict__ gam,
    const float* __restrict__ bet, unsigned short* __restrict__ nf)
{
    int u = blockIdx.x;            // 0..8191 (= b*2048 + t)
    int tid = threadIdx.x;         // 0..191
    __shared__ float feat[C_];
    __shared__ float4 red4[4][48];
    __shared__ float red[4];
    __shared__ float stats[2];

    const float4* xb4 = (const float4*)(x + (size_t)u * (HWS * C_)); // 48 f4/row
    int cg = tid % 48;
    int rg = tid / 48;             // 0..3
    float4 a = make_float4(0.f, 0.f, 0.f, 0.f);
    #pragma unroll
    for (int s = 0; s < HWS; s += 4) {
        float4 v = xb4[(size_t)(s + rg) * 48 + cg];
        a.x += v.x; a.y += v.y; a.z += v.z; a.w += v.w;
    }
    red4[rg][cg] = a;
    __syncthreads();
    if (rg == 0) {
        float4 b0 = red4[0][cg], b1 = red4[1][cg], b2 = red4[2][cg], b3 = red4[3][cg];
        feat[cg * 4 + 0] = (b0.x + b1.x + b2.x + b3.x) * (1.0f / HWS);
        feat[cg * 4 + 1] = (b0.y + b1.y + b2.y + b3.y) * (1.0f / HWS);
        feat[cg * 4 + 2] = (b0.z + b1.z + b2.z + b3.z) * (1.0f / HWS);
        feat[cg * 4 + 3] = (b0.w + b1.w + b2.w + b3.w) * (1.0f / HWS);
    }
    __syncthreads();

    float h = 0.f;
    if (tid < G_) {
        h = bias[tid];
        #pragma unroll 4
        for (int c = 0; c < C_; ++c) h += feat[c] * W[c * G_ + tid];
    }
    float s1 = (tid < G_) ? h : 0.f;
    float s2 = (tid < G_) ? h * h : 0.f;
    #pragma unroll
    for (int off = 32; off >= 1; off >>= 1) {
        s1 += __shfl_xor(s1, off, 64);
        s2 += __shfl_xor(s2, off, 64);
    }
    int wid = tid >> 6;
    if ((tid & 63) == 0 && wid < 2) { red[wid] = s1; red[2 + wid] = s2; }
    __syncthreads();
    if (tid == 0) {
        float S = red[0] + red[1];
        float SS = red[2] + red[3];
        float mu = S / G_;
        float var = SS / G_ - mu * mu;
        stats[0] = mu;
        stats[1] = 1.0f / sqrtf(var + 1e-5f);
    }
    __syncthreads();
    if (tid < G_) {
        float v = (h - stats[0]) * stats[1] * gam[tid] + bet[tid];
        nf[(size_t)u * G_ + tid] = f2bf(v);
    }
}

// ================= mega kernel: shared-memory union =====================
struct ShR {
    char raw[HALO_ROWS * 256];              // 12288
    char agg[R_ * 1024];                    // 16384
    float smu[G_], sivg[G_], sbet[G_];      // 1536
    float sred[2][G_], ssred[2][G_];        // 2048
};
struct ShQ {
    char raw[HALO_ROWS * 256];              // 12288
    unsigned short kls[HALO_ROWS * 64];     // 6144
    unsigned short vls[HALO_ROWS * 64];     // 6144
    unsigned short qls[R_ * 64];            // 2048
    float sls[R_ * 64];                     // 4096
    float redsc[512];                       // 2048  (dedicated reduce scratch)
};
struct ShB {
    float smu[G_], sinv[G_];
    float sred[2][G_], ssred[2][G_];
};
union ShU { ShR r; ShQ q; ShB b; };

// ------ rgcn phase: [optional BN+lReLU input] + aggregate + GEMM --------
template <bool BNIN>
__device__ __forceinline__ void rgcn_phase(
    ShR& sh,
    const unsigned short* __restrict__ nf, const float* __restrict__ xin,
    const float* __restrict__ partials, const float* __restrict__ gam,
    const float* __restrict__ bet,
    const unsigned short* __restrict__ wt, const float* __restrict__ rb,
    unsigned short* __restrict__ out, int blk, int tid)
{
    char* raw = sh.raw;
    char* agg = sh.agg;
    int b = blk >> 7;
    int t0 = (blk & 127) * R_;

    if constexpr (BNIN) {
        int halfk = tid >> 7;          // 0/1
        int c = tid & 127;
        float s = 0.f, ss = 0.f;
        const float* P = partials + (size_t)b * 128 * 256;
        #pragma unroll 4
        for (int k = halfk * 64; k < halfk * 64 + 64; ++k) {
            s += P[k * 256 + c];
            ss += P[k * 256 + G_ + c];
        }
        sh.sred[halfk][c] = s;
        sh.ssred[halfk][c] = ss;
        __syncthreads();
        if (tid < G_) {
            float S = sh.sred[0][tid] + sh.sred[1][tid];
            float SS = sh.ssred[0][tid] + sh.ssred[1][tid];
            float mu = S / D_;
            float var = SS / D_ - mu * mu;
            float inv = 1.0f / sqrtf(var + 1e-5f);
            sh.smu[tid] = mu;
            sh.sivg[tid] = inv * gam[tid];
            sh.sbet[tid] = bet[tid];
        }
        __syncthreads();
        const float* xb = xin + (size_t)b * D_ * G_;
        #pragma unroll
        for (int p = 0; p < 3; ++p) {
            int task = tid + p * 256;
            int i = task >> 4, c16 = task & 15;
            int t = t0 - 15 + i;
            bf8_t v8 = {0, 0, 0, 0, 0, 0, 0, 0};
            if (t >= 0 && t < D_) {
                const float* vp = xb + (size_t)t * G_ + c16 * 8;
                #pragma unroll
                for (int e = 0; e < 8; ++e) {
                    int c = c16 * 8 + e;
                    float yv = (vp[e] - sh.smu[c]) * sh.sivg[c] + sh.sbet[c];
                    yv = (yv > 0.f) ? yv : 0.01f * yv;
                    v8[e] = (short)f2bf(yv);
                }
            }
            *(bf8_t*)(raw + ((i * 256 + c16 * 16) ^ ((i & 7) << 4))) = v8;
        }
    } else {
        const unsigned short* src = nf + (size_t)b * D_ * G_;
        #pragma unroll
        for (int p = 0; p < 3; ++p) {
            int task = tid + p * 256;
            int i = task >> 4, c16 = task & 15;
            int t = t0 - 15 + i;
            bf8_t v = {0, 0, 0, 0, 0, 0, 0, 0};
            if (t >= 0 && t < D_) v = *(const bf8_t*)(src + (size_t)t * G_ + c16 * 8);
            *(bf8_t*)(raw + ((i * 256 + c16 * 16) ^ ((i & 7) << 4))) = v;
        }
    }
    __syncthreads();

    #pragma unroll
    for (int p = 0; p < 4; ++p) {
        int task = tid + p * 256;
        int c16 = task & 15, rel = (task >> 4) & 3, row = task >> 6;   // row 0..15
        int t = t0 + row;
        int ctr = row + 15;
        float s[8] = {0.f,0.f,0.f,0.f,0.f,0.f,0.f,0.f};
        float scale = 1.f;
        if (rel == 0) {
            bf8_t v = *(const bf8_t*)(raw + ((ctr * 256 + c16 * 16) ^ ((ctr & 7) << 4)));
            #pragma unroll
            for (int e = 0; e < 8; ++e) s[e] = bf2f((unsigned short)v[e]);
        } else if (rel == 1) {
            #pragma unroll
            for (int o = 1; o <= 5; ++o) if (t + o < D_) {
                int i = ctr + o;
                bf8_t v = *(const bf8_t*)(raw + ((i * 256 + c16 * 16) ^ ((i & 7) << 4)));
                #pragma unroll
                for (int e = 0; e < 8; ++e) s[e] += bf2f((unsigned short)v[e]);
            }
            scale = 1.f / (float)max(min(5, D_ - 1 - t), 1);
        } else if (rel == 2) {
            #pragma unroll
            for (int o = 1; o <= 5; ++o) if (t - o >= 0) {
                int i = ctr - o;
                bf8_t v = *(const bf8_t*)(raw + ((i * 256 + c16 * 16) ^ ((i & 7) << 4)));
                #pragma unroll
                for (int e = 0; e < 8; ++e) s[e] += bf2f((unsigned short)v[e]);
            }
            scale = 1.f / (float)max(min(5, t), 1);
        } else {
            int cnt = 0;
            if (t >= 15) {
                int i = ctr - 15;
                bf8_t v = *(const bf8_t*)(raw + ((i * 256 + c16 * 16) ^ ((i & 7) << 4)));
                #pragma unroll
                for (int e = 0; e < 8; ++e) s[e] += bf2f((unsigned short)v[e]);
                cnt++;
            }
            if (t + 15 < D_) {
                int i = ctr + 15;
                bf8_t v = *(const bf8_t*)(raw + ((i * 256 + c16 * 16) ^ ((i & 7) << 4)));
                #pragma unroll
                for (int e = 0; e < 8; ++e) s[e] += bf2f((unsigned short)v[e]);
                cnt++;
            }
            scale = 1.f / (float)max(cnt, 1);
        }
        bf8_t o8;
        #pragma unroll
        for (int e = 0; e < 8; ++e) o8[e] = (short)f2bf(s[e] * scale);
        *(bf8_t*)(agg + ((row * 1024 + rel * 256 + c16 * 16) ^ ((row & 7) << 4))) = o8;
    }
    __syncthreads();

    int l = tid & 63, wv = tid >> 6;
    int l15 = l & 15, kgrp = l >> 4;
    unsigned short* outb = out + (size_t)b * D_ * G_;
    int rbase = t0 + kgrp * 4;

    #pragma unroll
    for (int y = 0; y < 2; ++y) {
        int col16 = y * 4 + wv;
        f32x4_t acc = (f32x4_t){0.f, 0.f, 0.f, 0.f};
        for (int ks = 0; ks < 16; ++ks) {
            int rel = ks >> 2, kk = ks & 3;
            bf8_t a = *(const bf8_t*)(agg +
                ((l15 * 1024 + rel * 256 + kk * 64 + kgrp * 16) ^ ((l15 & 7) << 4)));
            bf8_t bf = *(const bf8_t*)(wt + rel * 16384 +
                (size_t)(col16 * 16 + l15) * G_ + kk * 32 + kgrp * 8);
            acc = __builtin_amdgcn_mfma_f32_16x16x32_bf16(a, bf, acc, 0, 0, 0);
        }
        int col = col16 * 16 + l15;
        float rbv = rb[col];
        #pragma unroll
        for (int j = 0; j < 4; ++j)
            outb[(size_t)(rbase + j) * G_ + col] = f2bf(acc[j] + rbv);
    }
}

// ------ qkvs phase: GEMM + attention + BN partials (y looped) -----------
__device__ __forceinline__ void qkvs_phase(
    ShQ& sh,
    const unsigned short* __restrict__ nf1,
    const unsigned short* __restrict__ wt,
    const float* __restrict__ bq, const float* __restrict__ bk,
    const float* __restrict__ bv, const float* __restrict__ bsk,
    float* __restrict__ out2, float* __restrict__ partials,
    int blk, int tid)
{
    char* raw = sh.raw;
    int b = blk >> 7, t0 = (blk & 127) * R_;

    {
        const unsigned short* src = nf1 + (size_t)b * D_ * G_;
        #pragma unroll
        for (int p = 0; p < 3; ++p) {
            int task = tid + p * 256;
            int i = task >> 4, c16 = task & 15;
            int t = t0 - 15 + i;
            bf8_t v = {0, 0, 0, 0, 0, 0, 0, 0};
            if (t >= 0 && t < D_) v = *(const bf8_t*)(src + (size_t)t * G_ + c16 * 8);
            *(bf8_t*)(raw + ((i * 256 + c16 * 16) ^ ((i & 7) << 4))) = v;
        }
    }
    __syncthreads();

    int l = tid & 63, wvid = tid >> 6;
    int l15 = l & 15, kgrp = l >> 4;
    const float invs = 0.17677669529663687f;  // 1/sqrt(32)
    const int offs[13] = {0, 1, 2, 3, 4, 5, -1, -2, -3, -4, -5, -15, 15};
    float* o2b = out2 + (size_t)b * D_ * G_;

    for (int y = 0; y < 2; ++y) {
        #pragma unroll
        for (int i = 0; i < 2; ++i) {
            int job = wvid + i * 4;
            int m, frag;
            if (job < 3)      { m = 1; frag = job; }        // K
            else if (job < 6) { m = 2; frag = job - 3; }    // V
            else if (job == 6){ m = 0; frag = 0; }          // Q
            else              { m = 3; frag = 0; }          // S
            bool halo = (m == 1) | (m == 2);
            int rawrow = halo ? (frag * 16 + l15) : (15 + l15);
            const unsigned short* wm = wt + (size_t)m * 16384;
            const float* bias = (m == 0) ? bq : (m == 1) ? bk : (m == 2) ? bv : bsk;

            bf8_t a[4];
            #pragma unroll
            for (int kc = 0; kc < 4; ++kc)
                a[kc] = *(const bf8_t*)(raw +
                    ((rawrow * 256 + kc * 64 + kgrp * 16) ^ ((rawrow & 7) << 4)));
            f32x4_t acc[4];
            #pragma unroll
            for (int n = 0; n < 4; ++n) acc[n] = (f32x4_t){0.f, 0.f, 0.f, 0.f};
            #pragma unroll
            for (int kc = 0; kc < 4; ++kc) {
                #pragma unroll
                for (int n = 0; n < 4; ++n) {
                    int col = y * 64 + n * 16 + l15;
                    bf8_t bf = *(const bf8_t*)(wm +
                        (size_t)col * G_ + kc * 32 + kgrp * 8);
                    acc[n] = __builtin_amdgcn_mfma_f32_16x16x32_bf16(a[kc], bf, acc[n], 0, 0, 0);
                }
            }
            int r0 = frag * 16 + kgrp * 4;
            #pragma unroll
            for (int n = 0; n < 4; ++n) {
                int ln = n * 16 + l15;              // local col 0..63
                float bb = bias[y * 64 + ln];
                #pragma unroll
                for (int j = 0; j < 4; ++j) {
                    float v = acc[n][j] + bb;
                    int rr = r0 + j;
                    if (m == 1)      sh.kls[rr * 64 + ln] = f2bf(v);
                    else if (m == 2) sh.vls[rr * 64 + ln] = f2bf(v);
                    else if (m == 0) sh.qls[rr * 64 + ln] = f2bf(v);
                    else             sh.sls[rr * 64 + ln] = v;
                }
            }
        }
        __syncthreads();

        int j = tid & 63, quarter = tid >> 6;
        float ps = 0.f, pss = 0.f;
        for (int it = 0; it < 4; ++it) {
            int tl = it * 4 + quarter;         // 0..15
            int t = t0 + tl;
            float q = bf2f(sh.qls[tl * 64 + j]);
            float lg[13], vv[13];
            #pragma unroll
            for (int n = 0; n < 13; ++n) {
                int ts = t + offs[n];
                bool ok = (ts >= 0) && (ts < D_);
                int ki = tl + 15 + offs[n];    // 0..45
                float kk = ok ? bf2f(sh.kls[ki * 64 + j]) : 0.f;
                vv[n] = ok ? bf2f(sh.vls[ki * 64 + j]) : 0.f;
                float p = q * kk;
                p += __shfl_xor(p, 16, 32);
                p += __shfl_xor(p, 8, 32);
                p += __shfl_xor(p, 4, 32);
                p += __shfl_xor(p, 2, 32);
                p += __shfl_xor(p, 1, 32);
                lg[n] = ok ? p * invs : -1e30f;
            }
            float m = lg[0];
            #pragma unroll
            for (int n = 1; n < 13; ++n) m = fmaxf(m, lg[n]);
            float den = 0.f, aggv = 0.f;
            #pragma unroll
            for (int n = 0; n < 13; ++n) {
                float e = expf(lg[n] - m);
                den += e;
                aggv += e * vv[n];
            }
            float o = aggv / den + sh.sls[tl * 64 + j];
            o2b[(size_t)t * G_ + y * 64 + j] = o;
            ps += o; pss += o * o;
        }
        __syncthreads();

        sh.redsc[quarter * 64 + j] = ps;
        sh.redsc[256 + quarter * 64 + j] = pss;
        __syncthreads();
        if (tid < 64) {
            float s = 0.f, ss = 0.f;
            #pragma unroll
            for (int qq = 0; qq < 4; ++qq) {
                s += sh.redsc[qq * 64 + tid];
                ss += sh.redsc[256 + qq * 64 + tid];
            }
            float* P = partials + ((size_t)b * 128 + (blk & 127)) * 256;
            P[y * 64 + tid] = s;
            P[128 + y * 64 + tid] = ss;
        }
        __syncthreads();
    }
}

// ------ bn_final phase: stats + norm + lReLU -> d_out (16 rows/block) ---
__device__ __forceinline__ void bn_final_phase(
    ShB& sh,
    const float* __restrict__ X, const float* __restrict__ partials,
    const float* __restrict__ gam, const float* __restrict__ bet,
    float* __restrict__ out, int blk, int tid)
{
    int b = blk >> 7;           // 0..3
    int chunk = blk & 127;      // 16-row slice
    {
        int halfk = tid >> 7;
        int c = tid & 127;
        float s = 0.f, ss = 0.f;
        const float* P = partials + (size_t)b * 128 * 256;
        #pragma unroll 4
        for (int k = halfk * 64; k < halfk * 64 + 64; ++k) {
            s += P[k * 256 + c];
            ss += P[k * 256 + G_ + c];
        }
        sh.sred[halfk][c] = s;
        sh.ssred[halfk][c] = ss;
    }
    __syncthreads();
    if (tid < G_) {
        float S = sh.sred[0][tid] + sh.sred[1][tid];
        float SS = sh.ssred[0][tid] + sh.ssred[1][tid];
        float mu = S / D_;
        float var = SS / D_ - mu * mu;
        sh.smu[tid] = mu;
        sh.sinv[tid] = 1.0f / sqrtf(var + 1e-5f);
    }
    __syncthreads();

    const float4* base4 = (const float4*)(X + ((size_t)b * D_ + chunk * 16) * G_);
    float4* ob4 = (float4*)(out + ((size_t)b * D_ + chunk * 16) * G_);
    int c4 = (tid & 31) * 4;
    float m0 = sh.smu[c4], m1 = sh.smu[c4 + 1], m2 = sh.smu[c4 + 2], m3 = sh.smu[c4 + 3];
    float i0 = sh.sinv[c4] * gam[c4],     i1 = sh.sinv[c4 + 1] * gam[c4 + 1];
    float i2 = sh.sinv[c4 + 2] * gam[c4 + 2], i3 = sh.sinv[c4 + 3] * gam[c4 + 3];
    float b0 = bet[c4], b1 = bet[c4 + 1], b2 = bet[c4 + 2], b3 = bet[c4 + 3];
    #pragma unroll
    for (int p = 0; p < 2; ++p) {
        float4 v = base4[p * 256 + tid];
        float4 y;
        y.x = (v.x - m0) * i0 + b0;
        y.y = (v.y - m1) * i1 + b1;
        y.z = (v.z - m2) * i2 + b2;
        y.w = (v.w - m3) * i3 + b3;
        y.x = (y.x > 0.f) ? y.x : 0.01f * y.x;
        y.y = (y.y > 0.f) ? y.y : 0.01f * y.y;
        y.z = (y.z > 0.f) ? y.z : 0.01f * y.z;
        y.w = (y.w > 0.f) ? y.w : 0.01f * y.w;
        ob4[p * 256 + tid] = y;
    }
}

// ------ persistent mega kernel (grid 512 = 2 blocks/CU exactly) ---------
struct MegaArgs {
    const unsigned short* nf;
    unsigned short* nf1;
    float* out2;
    float* partials;
    const unsigned short* wbf;
    const float* rgcn_b;
    const float* bq; const float* bk; const float* bv; const float* bsk;
    const float* bn_g; const float* bn_b;
    float* dout;
    unsigned* counters;     // 4 slots, zeroed per launch
};

__global__ __launch_bounds__(256, 2) void mega_kernel(MegaArgs a)
{
    __shared__ ShU sh;
    int blk = blockIdx.x;           // 0..511
    int tid = threadIdx.x;

    // layer 0
    rgcn_phase<false>(sh.r, a.nf, nullptr, nullptr, nullptr, nullptr,
                      a.wbf, a.rgcn_b, a.nf1, blk, tid);
    gbar(a.counters + 0, tid);

    qkvs_phase(sh.q, a.nf1, a.wbf + (size_t)4 * 16384,
               a.bq, a.bk, a.bv, a.bsk, a.out2, a.partials, blk, tid);
    gbar(a.counters + 1, tid);

    // layer 1 (layer-0 BN folded into rgcn staging)
    rgcn_phase<true>(sh.r, nullptr, a.out2, a.partials, a.bn_g, a.bn_b,
                     a.wbf + (size_t)8 * 16384, a.rgcn_b + G_, a.nf1, blk, tid);
    gbar(a.counters + 2, tid);

    qkvs_phase(sh.q, a.nf1, a.wbf + (size_t)12 * 16384,
               a.bq + G_, a.bk + G_, a.bv + G_, a.bsk + G_,
               a.out2, a.partials, blk, tid);
    gbar(a.counters + 3, tid);

    bn_final_phase(sh.b, a.out2, a.partials, a.bn_g + G_, a.bn_b + G_,
                   a.dout, blk, tid);
}

extern "C" void kernel_launch(void* const* d_in, const int* in_sizes, int n_in,
                              void* d_out, int out_size, void* d_ws, size_t ws_size,
                              hipStream_t stream)
{
    (void)in_sizes; (void)n_in; (void)out_size; (void)ws_size;
    const float* x      = (const float*)d_in[0];
    const float* fe_w   = (const float*)d_in[3];
    const float* fe_b   = (const float*)d_in[4];
    const float* ln_g   = (const float*)d_in[5];
    const float* ln_b   = (const float*)d_in[6];
    const float* w_rel  = (const float*)d_in[7];   // [2][4][128][128]
    const float* w_root = (const float*)d_in[8];   // [2][128][128]
    const float* rgcn_b = (const float*)d_in[9];   // [2][128]
    const float* wq  = (const float*)d_in[10];
    const float* bq  = (const float*)d_in[11];
    const float* wk  = (const float*)d_in[12];
    const float* bk  = (const float*)d_in[13];
    const float* wv  = (const float*)d_in[14];
    const float* bv  = (const float*)d_in[15];
    const float* wsk = (const float*)d_in[16];
    const float* bsk = (const float*)d_in[17];
    const float* bn_g = (const float*)d_in[18];
    const float* bn_b = (const float*)d_in[19];

    float* ws   = (float*)d_ws;
    float* out2 = ws;                                  // [8192][128] f32
    float* partials = out2 + (size_t)NODES * G_;       // [4][128][256] f32
    unsigned short* nf_bf  = (unsigned short*)(partials + 4 * 128 * 256);
    unsigned short* nf1_bf = nf_bf + (size_t)NODES * G_;
    unsigned short* wbf    = nf1_bf + (size_t)NODES * G_;   // 16 x [128][128]
    unsigned* counters     = (unsigned*)(wbf + (size_t)16 * 16384);

    hipMemsetAsync(counters, 0, 4 * sizeof(unsigned), stream);

    WconvArgs wa;
    for (int l = 0; l < 2; ++l) {
        for (int r = 0; r < 4; ++r) {
            wa.src[l * 8 + r] = w_rel + ((size_t)l * 4 + r) * G_ * G_;
            wa.add[l * 8 + r] = (r == 0) ? (w_root + (size_t)l * G_ * G_) : nullptr;
        }
        wa.src[l * 8 + 4] = wq  + (size_t)l * G_ * G_; wa.add[l * 8 + 4] = nullptr;
        wa.src[l * 8 + 5] = wk  + (size_t)l * G_ * G_; wa.add[l * 8 + 5] = nullptr;
        wa.src[l * 8 + 6] = wv  + (size_t)l * G_ * G_; wa.add[l * 8 + 6] = nullptr;
        wa.src[l * 8 + 7] = wsk + (size_t)l * G_ * G_; wa.add[l * 8 + 7] = nullptr;
    }
    wconv_kernel<<<dim3(64, 16), 256, 0, stream>>>(wa, wbf);

    pool_fc_ln_kernel<<<NODES, 192, 0, stream>>>(x, fe_w, fe_b, ln_g, ln_b, nf_bf);

    MegaArgs ma;
    ma.nf = nf_bf; ma.nf1 = nf1_bf; ma.out2 = out2; ma.partials = partials;
    ma.wbf = wbf; ma.rgcn_b = rgcn_b;
    ma.bq = bq; ma.bk = bk; ma.bv = bv; ma.bsk = bsk;
    ma.bn_g = bn_g; ma.bn_b = bn_b; ma.dout = (float*)d_out;
    ma.counters = counters;
    mega_kernel<<<NBLK, 256, 0, stream>>>(ma);
}

// Round 15
// 298.047 us; speedup vs baseline: 2.1040x; 2.1040x over previous
//
#include <hip/hip_runtime.h>
#include <hip/hip_bf16.h>

#define B_ 4
#define D_ 2048
#define HWS 64
#define C_ 192
#define G_ 128
#define NODES (B_*D_)   // 8192
#define R_ 16           // central rows per block
#define NF1R 48         // nf1 rows computed per block (t0-15 .. t0+32)
#define RAWR 78         // staged input rows (t0-30 .. t0+47)

typedef short bf8_t  __attribute__((ext_vector_type(8)));   // 8 bf16 (4 VGPR)
typedef float f32x4_t __attribute__((ext_vector_type(4)));

__device__ inline unsigned short f2bf(float f) {
    unsigned int u = __builtin_bit_cast(unsigned int, f);
    unsigned int r = (u + 0x7fffu + ((u >> 16) & 1u)) >> 16;   // RNE
    return (unsigned short)r;
}
__device__ inline float bf2f(unsigned short h) {
    unsigned int u = ((unsigned int)h) << 16;
    return __builtin_bit_cast(float, u);
}

// ---------------- K0: weight conversion to bf16 WT[n][k] (+root fold) ---
struct WconvArgs {
    const float* src[16];
    const float* add[16];   // null or w_root slice (folded into slot 0)
};
__global__ __launch_bounds__(256) void wconv_kernel(WconvArgs a, unsigned short* __restrict__ dst)
{
    int m = blockIdx.y;
    int idx = blockIdx.x * 256 + threadIdx.x;   // n*128 + k
    int n = idx >> 7;
    int k = idx & 127;
    float v = a.src[m][k * G_ + n];
    if (a.add[m]) v += a.add[m][k * G_ + n];
    dst[(size_t)m * 16384 + idx] = f2bf(v);
}

// ---------------- K1: spatial mean-pool + FC + LayerNorm (-> bf16) ------
// PROVEN — unchanged from r9/r11.
__global__ __launch_bounds__(192) void pool_fc_ln_kernel(
    const float* __restrict__ x, const float* __restrict__ W,
    const float* __restrict__ bias, const float* __restrict__ gam,
    const float* __restrict__ bet, unsigned short* __restrict__ nf)
{
    int u = blockIdx.x;            // 0..8191 (= b*2048 + t)
    int tid = threadIdx.x;         // 0..191
    __shared__ float feat[C_];
    __shared__ float4 red4[4][48];
    __shared__ float red[4];
    __shared__ float stats[2];

    const float4* xb4 = (const float4*)(x + (size_t)u * (HWS * C_)); // 48 f4/row
    int cg = tid % 48;
    int rg = tid / 48;             // 0..3
    float4 a = make_float4(0.f, 0.f, 0.f, 0.f);
    #pragma unroll
    for (int s = 0; s < HWS; s += 4) {
        float4 v = xb4[(size_t)(s + rg) * 48 + cg];
        a.x += v.x; a.y += v.y; a.z += v.z; a.w += v.w;
    }
    red4[rg][cg] = a;
    __syncthreads();
    if (rg == 0) {
        float4 b0 = red4[0][cg], b1 = red4[1][cg], b2 = red4[2][cg], b3 = red4[3][cg];
        feat[cg * 4 + 0] = (b0.x + b1.x + b2.x + b3.x) * (1.0f / HWS);
        feat[cg * 4 + 1] = (b0.y + b1.y + b2.y + b3.y) * (1.0f / HWS);
        feat[cg * 4 + 2] = (b0.z + b1.z + b2.z + b3.z) * (1.0f / HWS);
        feat[cg * 4 + 3] = (b0.w + b1.w + b2.w + b3.w) * (1.0f / HWS);
    }
    __syncthreads();

    float h = 0.f;
    if (tid < G_) {
        h = bias[tid];
        #pragma unroll 4
        for (int c = 0; c < C_; ++c) h += feat[c] * W[c * G_ + tid];
    }
    float s1 = (tid < G_) ? h : 0.f;
    float s2 = (tid < G_) ? h * h : 0.f;
    #pragma unroll
    for (int off = 32; off >= 1; off >>= 1) {
        s1 += __shfl_xor(s1, off, 64);
        s2 += __shfl_xor(s2, off, 64);
    }
    int wid = tid >> 6;
    if ((tid & 63) == 0 && wid < 2) { red[wid] = s1; red[2 + wid] = s2; }
    __syncthreads();
    if (tid == 0) {
        float S = red[0] + red[1];
        float SS = red[2] + red[3];
        float mu = S / G_;
        float var = SS / G_ - mu * mu;
        stats[0] = mu;
        stats[1] = 1.0f / sqrtf(var + 1e-5f);
    }
    __syncthreads();
    if (tid < G_) {
        float v = (h - stats[0]) * stats[1] * gam[tid] + bet[tid];
        nf[(size_t)u * G_ + tid] = f2bf(v);
    }
}

// ============== per-layer fused kernel: rgcn(+halo) + qkvs + attn =======
struct ShQOut {
    unsigned short kls[NF1R * 64];   // 6144
    unsigned short vls[NF1R * 64];   // 6144
    unsigned short qls[R_ * 64];     // 2048
    float sls[R_ * 64];              // 4096
    float redsc[512];                // 2048
};
struct ShBN {
    float smu[G_], sivg[G_], sbet[G_];
    float sred[2][G_], ssred[2][G_];
};
struct ShL {
    char raw[RAWR * 256];            // 19968 (swizzled input halo)
    char nf1e[NF1R * 256];           // 12288 (swizzled nf1, bf16)
    union {
        char agg[R_ * 1024];         // 16384 (per-pass aggregate)
        ShQOut q;                    // 20480
        ShBN bn;                     // 3584
    } u;
};

template <bool BNIN>
__global__ __launch_bounds__(256) void layer_kernel(
    const unsigned short* __restrict__ nfin,   // BNIN=false: bf16 input
    const float* __restrict__ xin,             // BNIN=true: f32 pre-BN input
    const float* __restrict__ partials_in,     // BNIN=true: BN partials
    const float* __restrict__ gam, const float* __restrict__ bet,
    const unsigned short* __restrict__ wt,     // 8 mats: rel0-3, q,k,v,skip
    const float* __restrict__ rb,
    const float* __restrict__ bq, const float* __restrict__ bk,
    const float* __restrict__ bv, const float* __restrict__ bsk,
    float* __restrict__ out2, float* __restrict__ partials_out)
{
    __shared__ ShL sh;
    int blk = blockIdx.x;          // 0..511
    int tid = threadIdx.x;
    int b = blk >> 7;
    int t0 = (blk & 127) * R_;

    // ---- stage RAWR input rows (t0-30 .. t0+47), swizzled ----
    if constexpr (BNIN) {
        // BN stats from partials_in (proven halved-reduce)
        {
            int halfk = tid >> 7;
            int c = tid & 127;
            float s = 0.f, ss = 0.f;
            const float* P = partials_in + (size_t)b * 128 * 256;
            #pragma unroll 4
            for (int k = halfk * 64; k < halfk * 64 + 64; ++k) {
                s += P[k * 256 + c];
                ss += P[k * 256 + G_ + c];
            }
            sh.u.bn.sred[halfk][c] = s;
            sh.u.bn.ssred[halfk][c] = ss;
        }
        __syncthreads();
        if (tid < G_) {
            float S = sh.u.bn.sred[0][tid] + sh.u.bn.sred[1][tid];
            float SS = sh.u.bn.ssred[0][tid] + sh.u.bn.ssred[1][tid];
            float mu = S / D_;
            float var = SS / D_ - mu * mu;
            float inv = 1.0f / sqrtf(var + 1e-5f);
            sh.u.bn.smu[tid] = mu;
            sh.u.bn.sivg[tid] = inv * gam[tid];
            sh.u.bn.sbet[tid] = bet[tid];
        }
        __syncthreads();
        const float* xb = xin + (size_t)b * D_ * G_;
        #pragma unroll
        for (int p = 0; p < 5; ++p) {
            int task = tid + p * 256;
            if (task < RAWR * 16) {
                int i = task >> 4, c16 = task & 15;
                int t = t0 - 30 + i;
                bf8_t v8 = {0, 0, 0, 0, 0, 0, 0, 0};
                if (t >= 0 && t < D_) {
                    const float* vp = xb + (size_t)t * G_ + c16 * 8;
                    #pragma unroll
                    for (int e = 0; e < 8; ++e) {
                        int c = c16 * 8 + e;
                        float yv = (vp[e] - sh.u.bn.smu[c]) * sh.u.bn.sivg[c] + sh.u.bn.sbet[c];
                        yv = (yv > 0.f) ? yv : 0.01f * yv;
                        v8[e] = (short)f2bf(yv);
                    }
                }
                *(bf8_t*)(sh.raw + ((i * 256 + c16 * 16) ^ ((i & 7) << 4))) = v8;
            }
        }
    } else {
        const unsigned short* src = nfin + (size_t)b * D_ * G_;
        #pragma unroll
        for (int p = 0; p < 5; ++p) {
            int task = tid + p * 256;
            if (task < RAWR * 16) {
                int i = task >> 4, c16 = task & 15;
                int t = t0 - 30 + i;
                bf8_t v = {0, 0, 0, 0, 0, 0, 0, 0};
                if (t >= 0 && t < D_) v = *(const bf8_t*)(src + (size_t)t * G_ + c16 * 8);
                *(bf8_t*)(sh.raw + ((i * 256 + c16 * 16) ^ ((i & 7) << 4))) = v;
            }
        }
    }
    __syncthreads();

    int l = tid & 63, wv = tid >> 6;
    int l15 = l & 15, kgrp = l >> 4;

    // ---- rgcn: 3 passes of 16 output rows (local rows 0..47) ----
    for (int ps = 0; ps < 3; ++ps) {
        // aggregate 16 rows x 4 rel x 16 chunks = 1024 tasks
        #pragma unroll
        for (int p = 0; p < 4; ++p) {
            int task = tid + p * 256;
            int c16 = task & 15, rel = (task >> 4) & 3, row = task >> 6;  // 0..15
            int pr = ps * 16 + row;            // local nf1 row 0..47
            int t = t0 - 15 + pr;              // may be out of [0,D)
            int ctr = pr + 15;                 // raw row of t
            float s[8] = {0.f,0.f,0.f,0.f,0.f,0.f,0.f,0.f};
            float scale = 1.f;
            if (rel == 0) {
                bf8_t v = *(const bf8_t*)(sh.raw + ((ctr * 256 + c16 * 16) ^ ((ctr & 7) << 4)));
                #pragma unroll
                for (int e = 0; e < 8; ++e) s[e] = bf2f((unsigned short)v[e]);
            } else if (rel == 1) {
                #pragma unroll
                for (int o = 1; o <= 5; ++o) if (t + o < D_ && t + o >= 0) {
                    int i = ctr + o;
                    bf8_t v = *(const bf8_t*)(sh.raw + ((i * 256 + c16 * 16) ^ ((i & 7) << 4)));
                    #pragma unroll
                    for (int e = 0; e < 8; ++e) s[e] += bf2f((unsigned short)v[e]);
                }
                scale = 1.f / (float)max(min(5, D_ - 1 - t), 1);
            } else if (rel == 2) {
                #pragma unroll
                for (int o = 1; o <= 5; ++o) if (t - o >= 0 && t - o < D_) {
                    int i = ctr - o;
                    bf8_t v = *(const bf8_t*)(sh.raw + ((i * 256 + c16 * 16) ^ ((i & 7) << 4)));
                    #pragma unroll
                    for (int e = 0; e < 8; ++e) s[e] += bf2f((unsigned short)v[e]);
                }
                scale = 1.f / (float)max(min(5, t), 1);
            } else {
                int cnt = 0;
                if (t >= 15 && t < D_ + 15) {
                    int i = ctr - 15;
                    bf8_t v = *(const bf8_t*)(sh.raw + ((i * 256 + c16 * 16) ^ ((i & 7) << 4)));
                    #pragma unroll
                    for (int e = 0; e < 8; ++e) s[e] += bf2f((unsigned short)v[e]);
                    cnt++;
                }
                if (t + 15 < D_ && t + 15 >= 0) {
                    int i = ctr + 15;
                    bf8_t v = *(const bf8_t*)(sh.raw + ((i * 256 + c16 * 16) ^ ((i & 7) << 4)));
                    #pragma unroll
                    for (int e = 0; e < 8; ++e) s[e] += bf2f((unsigned short)v[e]);
                    cnt++;
                }
                scale = 1.f / (float)max(cnt, 1);
            }
            bf8_t o8;
            #pragma unroll
            for (int e = 0; e < 8; ++e) o8[e] = (short)f2bf(s[e] * scale);
            *(bf8_t*)(sh.u.agg + ((row * 1024 + rel * 256 + c16 * 16) ^ ((row & 7) << 4))) = o8;
        }
        __syncthreads();

        // K=512 MFMA -> nf1e rows ps*16 .. ps*16+15 (all 128 cols)
        #pragma unroll
        for (int y = 0; y < 2; ++y) {
            int col16 = y * 4 + wv;
            f32x4_t acc = (f32x4_t){0.f, 0.f, 0.f, 0.f};
            for (int ks = 0; ks < 16; ++ks) {
                int rel = ks >> 2, kk = ks & 3;
                bf8_t a = *(const bf8_t*)(sh.u.agg +
                    ((l15 * 1024 + rel * 256 + kk * 64 + kgrp * 16) ^ ((l15 & 7) << 4)));
                bf8_t bf = *(const bf8_t*)(wt + rel * 16384 +
                    (size_t)(col16 * 16 + l15) * G_ + kk * 32 + kgrp * 8);
                acc = __builtin_amdgcn_mfma_f32_16x16x32_bf16(a, bf, acc, 0, 0, 0);
            }
            int col = col16 * 16 + l15;
            float rbv = rb[col];
            #pragma unroll
            for (int j = 0; j < 4; ++j) {
                int row = ps * 16 + kgrp * 4 + j;
                *(unsigned short*)(sh.nf1e +
                    ((row * 256 + col * 2) ^ ((row & 7) << 4))) = f2bf(acc[j] + rbv);
            }
        }
        __syncthreads();
    }

    // ---- qkvs GEMM from nf1e (rows 0..47), y-looped ----
    const float invs = 0.17677669529663687f;  // 1/sqrt(32)
    const int offs[13] = {0, 1, 2, 3, 4, 5, -1, -2, -3, -4, -5, -15, 15};
    float* o2b = out2 + (size_t)b * D_ * G_;

    for (int y = 0; y < 2; ++y) {
        #pragma unroll
        for (int i = 0; i < 2; ++i) {
            int job = wv + i * 4;
            int m, frag;
            if (job < 3)      { m = 1; frag = job; }        // K (rows 0..47)
            else if (job < 6) { m = 2; frag = job - 3; }    // V
            else if (job == 6){ m = 0; frag = 0; }          // Q (central)
            else              { m = 3; frag = 0; }          // S
            bool halo = (m == 1) | (m == 2);
            int nrow = halo ? (frag * 16 + l15) : (15 + l15);
            const unsigned short* wm = wt + (size_t)(4 + m) * 16384;
            const float* bias = (m == 0) ? bq : (m == 1) ? bk : (m == 2) ? bv : bsk;

            bf8_t a[4];
            #pragma unroll
            for (int kc = 0; kc < 4; ++kc)
                a[kc] = *(const bf8_t*)(sh.nf1e +
                    ((nrow * 256 + kc * 64 + kgrp * 16) ^ ((nrow & 7) << 4)));
            f32x4_t acc[4];
            #pragma unroll
            for (int n = 0; n < 4; ++n) acc[n] = (f32x4_t){0.f, 0.f, 0.f, 0.f};
            #pragma unroll
            for (int kc = 0; kc < 4; ++kc) {
                #pragma unroll
                for (int n = 0; n < 4; ++n) {
                    int col = y * 64 + n * 16 + l15;
                    bf8_t bf = *(const bf8_t*)(wm +
                        (size_t)col * G_ + kc * 32 + kgrp * 8);
                    acc[n] = __builtin_amdgcn_mfma_f32_16x16x32_bf16(a[kc], bf, acc[n], 0, 0, 0);
                }
            }
            int r0 = frag * 16 + kgrp * 4;
            #pragma unroll
            for (int n = 0; n < 4; ++n) {
                int ln = n * 16 + l15;              // local col 0..63
                float bb = bias[y * 64 + ln];
                #pragma unroll
                for (int j = 0; j < 4; ++j) {
                    float v = acc[n][j] + bb;
                    int rr = r0 + j;
                    if (m == 1)      sh.u.q.kls[rr * 64 + ln] = f2bf(v);
                    else if (m == 2) sh.u.q.vls[rr * 64 + ln] = f2bf(v);
                    else if (m == 0) sh.u.q.qls[rr * 64 + ln] = f2bf(v);
                    else             sh.u.q.sls[rr * 64 + ln] = v;
                }
            }
        }
        __syncthreads();

        int j = tid & 63, quarter = tid >> 6;
        float ps2 = 0.f, pss = 0.f;
        for (int it = 0; it < 4; ++it) {
            int tl = it * 4 + quarter;         // 0..15
            int t = t0 + tl;
            float q = bf2f(sh.u.q.qls[tl * 64 + j]);
            float lg[13], vv[13];
            #pragma unroll
            for (int n = 0; n < 13; ++n) {
                int ts = t + offs[n];
                bool ok = (ts >= 0) && (ts < D_);
                int ki = tl + 15 + offs[n];    // 0..45
                float kk = ok ? bf2f(sh.u.q.kls[ki * 64 + j]) : 0.f;
                vv[n] = ok ? bf2f(sh.u.q.vls[ki * 64 + j]) : 0.f;
                float p = q * kk;
                p += __shfl_xor(p, 16, 32);
                p += __shfl_xor(p, 8, 32);
                p += __shfl_xor(p, 4, 32);
                p += __shfl_xor(p, 2, 32);
                p += __shfl_xor(p, 1, 32);
                lg[n] = ok ? p * invs : -1e30f;
            }
            float m = lg[0];
            #pragma unroll
            for (int n = 1; n < 13; ++n) m = fmaxf(m, lg[n]);
            float den = 0.f, aggv = 0.f;
            #pragma unroll
            for (int n = 0; n < 13; ++n) {
                float e = expf(lg[n] - m);
                den += e;
                aggv += e * vv[n];
            }
            float o = aggv / den + sh.u.q.sls[tl * 64 + j];
            o2b[(size_t)t * G_ + y * 64 + j] = o;
            ps2 += o; pss += o * o;
        }
        __syncthreads();

        sh.u.q.redsc[quarter * 64 + j] = ps2;
        sh.u.q.redsc[256 + quarter * 64 + j] = pss;
        __syncthreads();
        if (tid < 64) {
            float s = 0.f, ss = 0.f;
            #pragma unroll
            for (int qq = 0; qq < 4; ++qq) {
                s += sh.u.q.redsc[qq * 64 + tid];
                ss += sh.u.q.redsc[256 + qq * 64 + tid];
            }
            float* P = partials_out + ((size_t)b * 128 + (blk & 127)) * 256;
            P[y * 64 + tid] = s;
            P[128 + y * 64 + tid] = ss;
        }
        __syncthreads();
    }
}

// ------ BatchNorm apply (final layer -> d_out, f32) — verbatim r11 ------
__global__ __launch_bounds__(256) void bn_apply_kernel(
    const float* __restrict__ X, const float* __restrict__ partials,
    const float* __restrict__ gam, const float* __restrict__ bet,
    float* __restrict__ out)
{
    int chunk = blockIdx.x;   // 0..31 (64-row slices)
    int b = blockIdx.y;
    int tid = threadIdx.x;
    __shared__ float smu[G_], sinv[G_];
    if (tid < G_) {
        float s = 0.f, ss = 0.f;
        const float* P = partials + (size_t)b * 128 * 256;
        #pragma unroll 4
        for (int k = 0; k < 128; ++k) {
            s += P[k * 256 + tid];
            ss += P[k * 256 + G_ + tid];
        }
        float mu = s / D_;
        float var = ss / D_ - mu * mu;
        smu[tid] = mu;
        sinv[tid] = 1.0f / sqrtf(var + 1e-5f);
    }
    __syncthreads();

    const float4* base4 = (const float4*)(X + ((size_t)b * D_ + chunk * 64) * G_);
    int c4 = (tid & 31) * 4;
    float m0 = smu[c4], m1 = smu[c4 + 1], m2 = smu[c4 + 2], m3 = smu[c4 + 3];
    float i0 = sinv[c4] * gam[c4],     i1 = sinv[c4 + 1] * gam[c4 + 1];
    float i2 = sinv[c4 + 2] * gam[c4 + 2], i3 = sinv[c4 + 3] * gam[c4 + 3];
    float b0 = bet[c4], b1 = bet[c4 + 1], b2 = bet[c4 + 2], b3 = bet[c4 + 3];
    #pragma unroll
    for (int p = 0; p < 8; ++p) {
        float4 v = base4[p * 256 + tid];
        float4 y;
        y.x = (v.x - m0) * i0 + b0;
        y.y = (v.y - m1) * i1 + b1;
        y.z = (v.z - m2) * i2 + b2;
        y.w = (v.w - m3) * i3 + b3;
        y.x = (y.x > 0.f) ? y.x : 0.01f * y.x;
        y.y = (y.y > 0.f) ? y.y : 0.01f * y.y;
        y.z = (y.z > 0.f) ? y.z : 0.01f * y.z;
        y.w = (y.w > 0.f) ? y.w : 0.01f * y.w;
        float4* ob = (float4*)(out + ((size_t)b * D_ + chunk * 64) * G_);
        ob[p * 256 + tid] = y;
    }
}

extern "C" void kernel_launch(void* const* d_in, const int* in_sizes, int n_in,
                              void* d_out, int out_size, void* d_ws, size_t ws_size,
                              hipStream_t stream)
{
    (void)in_sizes; (void)n_in; (void)out_size; (void)ws_size;
    const float* x      = (const float*)d_in[0];
    const float* fe_w   = (const float*)d_in[3];
    const float* fe_b   = (const float*)d_in[4];
    const float* ln_g   = (const float*)d_in[5];
    const float* ln_b   = (const float*)d_in[6];
    const float* w_rel  = (const float*)d_in[7];   // [2][4][128][128]
    const float* w_root = (const float*)d_in[8];   // [2][128][128]
    const float* rgcn_b = (const float*)d_in[9];   // [2][128]
    const float* wq  = (const float*)d_in[10];
    const float* bq  = (const float*)d_in[11];
    const float* wk  = (const float*)d_in[12];
    const float* bk  = (const float*)d_in[13];
    const float* wv  = (const float*)d_in[14];
    const float* bv  = (const float*)d_in[15];
    const float* wsk = (const float*)d_in[16];
    const float* bsk = (const float*)d_in[17];
    const float* bn_g = (const float*)d_in[18];
    const float* bn_b = (const float*)d_in[19];

    float* ws   = (float*)d_ws;
    float* out2a = ws;                                  // [8192][128] f32
    float* out2b = out2a + (size_t)NODES * G_;          // [8192][128] f32
    float* partialsA = out2b + (size_t)NODES * G_;      // [4][128][256] f32
    float* partialsB = partialsA + 4 * 128 * 256;       // [4][128][256] f32
    unsigned short* nf_bf = (unsigned short*)(partialsB + 4 * 128 * 256);
    unsigned short* wbf   = nf_bf + (size_t)NODES * G_; // 16 x [128][128]

    WconvArgs wa;
    for (int l = 0; l < 2; ++l) {
        for (int r = 0; r < 4; ++r) {
            wa.src[l * 8 + r] = w_rel + ((size_t)l * 4 + r) * G_ * G_;
            wa.add[l * 8 + r] = (r == 0) ? (w_root + (size_t)l * G_ * G_) : nullptr;
        }
        wa.src[l * 8 + 4] = wq  + (size_t)l * G_ * G_; wa.add[l * 8 + 4] = nullptr;
        wa.src[l * 8 + 5] = wk  + (size_t)l * G_ * G_; wa.add[l * 8 + 5] = nullptr;
        wa.src[l * 8 + 6] = wv  + (size_t)l * G_ * G_; wa.add[l * 8 + 6] = nullptr;
        wa.src[l * 8 + 7] = wsk + (size_t)l * G_ * G_; wa.add[l * 8 + 7] = nullptr;
    }
    wconv_kernel<<<dim3(64, 16), 256, 0, stream>>>(wa, wbf);

    pool_fc_ln_kernel<<<NODES, 192, 0, stream>>>(x, fe_w, fe_b, ln_g, ln_b, nf_bf);

    // layer 0: nf_bf -> out2a, partialsA
    layer_kernel<false><<<512, 256, 0, stream>>>(
        nf_bf, nullptr, nullptr, nullptr, nullptr,
        wbf, rgcn_b,
        bq, bk, bv, bsk, out2a, partialsA);

    // layer 1 (BN of layer-0 folded): out2a/partialsA -> out2b, partialsB
    layer_kernel<true><<<512, 256, 0, stream>>>(
        nullptr, out2a, partialsA, bn_g, bn_b,
        wbf + (size_t)8 * 16384, rgcn_b + G_,
        bq + G_, bk + G_, bv + G_, bsk + G_, out2b, partialsB);

    bn_apply_kernel<<<dim3(32, 4), 256, 0, stream>>>(
        out2b, partialsB, bn_g + G_, bn_b + G_, (float*)d_out);
}

// Round 16
// 214.171 us; speedup vs baseline: 2.9280x; 1.3916x over previous
//
#include <hip/hip_runtime.h>
#include <hip/hip_bf16.h>

#define B_ 4
#define D_ 2048
#define HWS 64
#define C_ 192
#define G_ 128
#define NODES (B_*D_)   // 8192
#define R_ 16           // central rows per fused block
#define HALO_ROWS 48    // t0-15 .. t0+32 staged

typedef short bf8_t  __attribute__((ext_vector_type(8)));   // 8 bf16 (4 VGPR)
typedef float f32x4_t __attribute__((ext_vector_type(4)));

__device__ inline unsigned short f2bf(float f) {
    unsigned int u = __builtin_bit_cast(unsigned int, f);
    unsigned int r = (u + 0x7fffu + ((u >> 16) & 1u)) >> 16;   // RNE
    return (unsigned short)r;
}
__device__ inline float bf2f(unsigned short h) {
    unsigned int u = ((unsigned int)h) << 16;
    return __builtin_bit_cast(float, u);
}

struct WconvArgs {
    const float* src[16];
    const float* add[16];   // null or w_root slice (folded into slot 0)
};

// ---------------- K1: pool + FC + LayerNorm  (+ folded weight conv) -----
// Pool/FC/LN body PROVEN (r9/r11). Weight conversion relocated to the tail
// of blocks 0..2047 (threads 0..127): 2048*128 = 16*16384 elements.
__global__ __launch_bounds__(192) void pool_fc_ln_kernel(
    const float* __restrict__ x, const float* __restrict__ W,
    const float* __restrict__ bias, const float* __restrict__ gam,
    const float* __restrict__ bet, unsigned short* __restrict__ nf,
    WconvArgs wa, unsigned short* __restrict__ wbf)
{
    int u = blockIdx.x;            // 0..8191 (= b*2048 + t)
    int tid = threadIdx.x;         // 0..191
    __shared__ float feat[C_];
    __shared__ float4 red4[4][48];
    __shared__ float red[4];
    __shared__ float stats[2];

    const float4* xb4 = (const float4*)(x + (size_t)u * (HWS * C_)); // 48 f4/row
    int cg = tid % 48;
    int rg = tid / 48;             // 0..3
    float4 a = make_float4(0.f, 0.f, 0.f, 0.f);
    #pragma unroll
    for (int s = 0; s < HWS; s += 4) {
        float4 v = xb4[(size_t)(s + rg) * 48 + cg];
        a.x += v.x; a.y += v.y; a.z += v.z; a.w += v.w;
    }
    red4[rg][cg] = a;
    __syncthreads();
    if (rg == 0) {
        float4 b0 = red4[0][cg], b1 = red4[1][cg], b2 = red4[2][cg], b3 = red4[3][cg];
        feat[cg * 4 + 0] = (b0.x + b1.x + b2.x + b3.x) * (1.0f / HWS);
        feat[cg * 4 + 1] = (b0.y + b1.y + b2.y + b3.y) * (1.0f / HWS);
        feat[cg * 4 + 2] = (b0.z + b1.z + b2.z + b3.z) * (1.0f / HWS);
        feat[cg * 4 + 3] = (b0.w + b1.w + b2.w + b3.w) * (1.0f / HWS);
    }
    __syncthreads();

    float h = 0.f;
    if (tid < G_) {
        h = bias[tid];
        #pragma unroll 4
        for (int c = 0; c < C_; ++c) h += feat[c] * W[c * G_ + tid];
    }
    float s1 = (tid < G_) ? h : 0.f;
    float s2 = (tid < G_) ? h * h : 0.f;
    #pragma unroll
    for (int off = 32; off >= 1; off >>= 1) {
        s1 += __shfl_xor(s1, off, 64);
        s2 += __shfl_xor(s2, off, 64);
    }
    int wid = tid >> 6;
    if ((tid & 63) == 0 && wid < 2) { red[wid] = s1; red[2 + wid] = s2; }
    __syncthreads();
    if (tid == 0) {
        float S = red[0] + red[1];
        float SS = red[2] + red[3];
        float mu = S / G_;
        float var = SS / G_ - mu * mu;
        stats[0] = mu;
        stats[1] = 1.0f / sqrtf(var + 1e-5f);
    }
    __syncthreads();
    if (tid < G_) {
        float v = (h - stats[0]) * stats[1] * gam[tid] + bet[tid];
        nf[(size_t)u * G_ + tid] = f2bf(v);
    }

    // ---- folded weight conversion (same math as old wconv_kernel) ----
    if (u < 2048 && tid < 128) {
        int idx = u * 128 + tid;           // 0..262143
        int m = idx >> 14;                 // 0..15
        int within = idx & 16383;          // n*128 + k
        int n = within >> 7, k = within & 127;
        float v = wa.src[m][k * G_ + n];
        if (wa.add[m]) v += wa.add[m][k * G_ + n];
        wbf[(size_t)m * 16384 + within] = f2bf(v);
    }
}

// ------ fused RGCN: [optional BN+lReLU on input] + aggregate + GEMM -----
// VERBATIM r11 (225.6 us champion).
template <bool BNIN>
__global__ __launch_bounds__(256) void rgcn_fused_kernel(
    const unsigned short* __restrict__ nf, const float* __restrict__ xin,
    const float* __restrict__ partials, const float* __restrict__ gam,
    const float* __restrict__ bet,
    const unsigned short* __restrict__ wt,   // 4 mats [128 n][128 k] bf16
    const float* __restrict__ rb,
    unsigned short* __restrict__ out)
{
    __shared__ char raw[HALO_ROWS * 256];   // 12 KB halo (swizzled)
    __shared__ char agg[R_ * 1024];         // 16 KB: [row][rel][128k] (swizzled)
    __shared__ float smu[G_], sivg[G_], sbet[G_];
    __shared__ float sred[2][G_], ssred[2][G_];
    int blk = blockIdx.x;
    int b = blk >> 7;
    int t0 = (blk & 127) * R_;
    int tid = threadIdx.x;

    if constexpr (BNIN) {
        int halfk = tid >> 7;          // 0/1
        int c = tid & 127;
        float s = 0.f, ss = 0.f;
        const float* P = partials + (size_t)b * 128 * 256;
        #pragma unroll 4
        for (int k = halfk * 64; k < halfk * 64 + 64; ++k) {
            s += P[k * 256 + c];
            ss += P[k * 256 + G_ + c];
        }
        sred[halfk][c] = s;
        ssred[halfk][c] = ss;
        __syncthreads();
        if (tid < G_) {
            float S = sred[0][tid] + sred[1][tid];
            float SS = ssred[0][tid] + ssred[1][tid];
            float mu = S / D_;
            float var = SS / D_ - mu * mu;
            float inv = 1.0f / sqrtf(var + 1e-5f);
            smu[tid] = mu;
            sivg[tid] = inv * gam[tid];
            sbet[tid] = bet[tid];
        }
        __syncthreads();
        const float* xb = xin + (size_t)b * D_ * G_;
        #pragma unroll
        for (int p = 0; p < 3; ++p) {
            int task = tid + p * 256;
            int i = task >> 4, c16 = task & 15;
            int t = t0 - 15 + i;
            bf8_t v8 = {0, 0, 0, 0, 0, 0, 0, 0};
            if (t >= 0 && t < D_) {
                const float* vp = xb + (size_t)t * G_ + c16 * 8;
                #pragma unroll
                for (int e = 0; e < 8; ++e) {
                    int c = c16 * 8 + e;
                    float yv = (vp[e] - smu[c]) * sivg[c] + sbet[c];
                    yv = (yv > 0.f) ? yv : 0.01f * yv;
                    v8[e] = (short)f2bf(yv);
                }
            }
            *(bf8_t*)(raw + ((i * 256 + c16 * 16) ^ ((i & 7) << 4))) = v8;
        }
    } else {
        const unsigned short* src = nf + (size_t)b * D_ * G_;
        #pragma unroll
        for (int p = 0; p < 3; ++p) {
            int task = tid + p * 256;        // 768 tasks = 48 rows x 16 chunks
            int i = task >> 4, c16 = task & 15;
            int t = t0 - 15 + i;
            bf8_t v = {0, 0, 0, 0, 0, 0, 0, 0};
            if (t >= 0 && t < D_) v = *(const bf8_t*)(src + (size_t)t * G_ + c16 * 8);
            *(bf8_t*)(raw + ((i * 256 + c16 * 16) ^ ((i & 7) << 4))) = v;
        }
    }
    __syncthreads();

    #pragma unroll
    for (int p = 0; p < 4; ++p) {
        int task = tid + p * 256;
        int c16 = task & 15, rel = (task >> 4) & 3, row = task >> 6;   // row 0..15
        int t = t0 + row;
        int ctr = row + 15;
        float s[8] = {0.f,0.f,0.f,0.f,0.f,0.f,0.f,0.f};
        float scale = 1.f;
        if (rel == 0) {
            bf8_t v = *(const bf8_t*)(raw + ((ctr * 256 + c16 * 16) ^ ((ctr & 7) << 4)));
            #pragma unroll
            for (int e = 0; e < 8; ++e) s[e] = bf2f((unsigned short)v[e]);
        } else if (rel == 1) {
            #pragma unroll
            for (int o = 1; o <= 5; ++o) if (t + o < D_) {
                int i = ctr + o;
                bf8_t v = *(const bf8_t*)(raw + ((i * 256 + c16 * 16) ^ ((i & 7) << 4)));
                #pragma unroll
                for (int e = 0; e < 8; ++e) s[e] += bf2f((unsigned short)v[e]);
            }
            scale = 1.f / (float)max(min(5, D_ - 1 - t), 1);
        } else if (rel == 2) {
            #pragma unroll
            for (int o = 1; o <= 5; ++o) if (t - o >= 0) {
                int i = ctr - o;
                bf8_t v = *(const bf8_t*)(raw + ((i * 256 + c16 * 16) ^ ((i & 7) << 4)));
                #pragma unroll
                for (int e = 0; e < 8; ++e) s[e] += bf2f((unsigned short)v[e]);
            }
            scale = 1.f / (float)max(min(5, t), 1);
        } else {
            int cnt = 0;
            if (t >= 15) {
                int i = ctr - 15;
                bf8_t v = *(const bf8_t*)(raw + ((i * 256 + c16 * 16) ^ ((i & 7) << 4)));
                #pragma unroll
                for (int e = 0; e < 8; ++e) s[e] += bf2f((unsigned short)v[e]);
                cnt++;
            }
            if (t + 15 < D_) {
                int i = ctr + 15;
                bf8_t v = *(const bf8_t*)(raw + ((i * 256 + c16 * 16) ^ ((i & 7) << 4)));
                #pragma unroll
                for (int e = 0; e < 8; ++e) s[e] += bf2f((unsigned short)v[e]);
                cnt++;
            }
            scale = 1.f / (float)max(cnt, 1);
        }
        bf8_t o8;
        #pragma unroll
        for (int e = 0; e < 8; ++e) o8[e] = (short)f2bf(s[e] * scale);
        *(bf8_t*)(agg + ((row * 1024 + rel * 256 + c16 * 16) ^ ((row & 7) << 4))) = o8;
    }
    __syncthreads();

    int l = tid & 63, wv = tid >> 6;
    int l15 = l & 15, kgrp = l >> 4;
    int col16 = blockIdx.y * 4 + wv;
    f32x4_t acc = (f32x4_t){0.f, 0.f, 0.f, 0.f};

    for (int ks = 0; ks < 16; ++ks) {
        int rel = ks >> 2, kk = ks & 3;
        bf8_t a = *(const bf8_t*)(agg +
            ((l15 * 1024 + rel * 256 + kk * 64 + kgrp * 16) ^ ((l15 & 7) << 4)));
        bf8_t bf = *(const bf8_t*)(wt + rel * 16384 +
            (size_t)(col16 * 16 + l15) * G_ + kk * 32 + kgrp * 8);
        acc = __builtin_amdgcn_mfma_f32_16x16x32_bf16(a, bf, acc, 0, 0, 0);
    }

    unsigned short* outb = out + (size_t)b * D_ * G_;
    int rbase = t0 + kgrp * 4;
    int col = col16 * 16 + l15;
    float rbv = rb[col];
    #pragma unroll
    for (int j = 0; j < 4; ++j)
        outb[(size_t)(rbase + j) * G_ + col] = f2bf(acc[j] + rbv);
}

// ---- helper: stage 48 halo rows of a bf16 [D][128] (qkvs staging) ------
__device__ inline void stage_halo48(const unsigned short* __restrict__ src,
                                    int t0, char* raw, int tid)
{
    #pragma unroll
    for (int p = 0; p < 3; ++p) {
        int task = tid + p * 256;        // 768 tasks = 48 rows x 16 chunks
        int i = task >> 4, c16 = task & 15;
        int t = t0 - 15 + i;
        bf8_t v = {0, 0, 0, 0, 0, 0, 0, 0};
        if (t >= 0 && t < D_) v = *(const bf8_t*)(src + (size_t)t * G_ + c16 * 8);
        *(bf8_t*)(raw + ((i * 256 + c16 * 16) ^ ((i & 7) << 4))) = v;
    }
}

// ------ fused QKVS GEMM + attention + BN partials, COL-SPLIT ------------
// VERBATIM r11.
__global__ __launch_bounds__(256) void qkvs_attn_kernel(
    const unsigned short* __restrict__ nf1,
    const unsigned short* __restrict__ wt,  // 4 mats: q,k,v,skip
    const float* __restrict__ bq, const float* __restrict__ bk,
    const float* __restrict__ bv, const float* __restrict__ bsk,
    float* __restrict__ out2, float* __restrict__ partials)
{
    __shared__ char raw[HALO_ROWS * 256];            // 12 KB (swizzled halo)
    __shared__ unsigned short kls[HALO_ROWS * 64];   // 6 KB
    __shared__ unsigned short vls[HALO_ROWS * 64];   // 6 KB
    __shared__ unsigned short qls[R_ * 64];          // 2 KB
    __shared__ float sls[R_ * 64];                   // 4 KB
    int blk = blockIdx.x, tid = threadIdx.x;
    int b = blk >> 7, t0 = (blk & 127) * R_;
    int y = blockIdx.y;

    stage_halo48(nf1 + (size_t)b * D_ * G_, t0, raw, tid);
    __syncthreads();

    int l = tid & 63, wvid = tid >> 6;
    int l15 = l & 15, kgrp = l >> 4;
    #pragma unroll
    for (int i = 0; i < 2; ++i) {
        int job = wvid + i * 4;
        int m, frag;
        if (job < 3)      { m = 1; frag = job; }        // K
        else if (job < 6) { m = 2; frag = job - 3; }    // V
        else if (job == 6){ m = 0; frag = 0; }          // Q
        else              { m = 3; frag = 0; }          // S
        bool halo = (m == 1) | (m == 2);
        int rawrow = halo ? (frag * 16 + l15) : (15 + l15);
        const unsigned short* wm = wt + (size_t)m * 16384;
        const float* bias = (m == 0) ? bq : (m == 1) ? bk : (m == 2) ? bv : bsk;

        bf8_t a[4];
        #pragma unroll
        for (int kc = 0; kc < 4; ++kc)
            a[kc] = *(const bf8_t*)(raw +
                ((rawrow * 256 + kc * 64 + kgrp * 16) ^ ((rawrow & 7) << 4)));
        f32x4_t acc[4];
        #pragma unroll
        for (int n = 0; n < 4; ++n) acc[n] = (f32x4_t){0.f, 0.f, 0.f, 0.f};
        #pragma unroll
        for (int kc = 0; kc < 4; ++kc) {
            #pragma unroll
            for (int n = 0; n < 4; ++n) {
                int col = y * 64 + n * 16 + l15;
                bf8_t bf = *(const bf8_t*)(wm +
                    (size_t)col * G_ + kc * 32 + kgrp * 8);
                acc[n] = __builtin_amdgcn_mfma_f32_16x16x32_bf16(a[kc], bf, acc[n], 0, 0, 0);
            }
        }
        int r0 = frag * 16 + kgrp * 4;
        #pragma unroll
        for (int n = 0; n < 4; ++n) {
            int ln = n * 16 + l15;              // local col 0..63
            float bb = bias[y * 64 + ln];
            #pragma unroll
            for (int j = 0; j < 4; ++j) {
                float v = acc[n][j] + bb;
                int rr = r0 + j;
                if (m == 1)      kls[rr * 64 + ln] = f2bf(v);
                else if (m == 2) vls[rr * 64 + ln] = f2bf(v);
                else if (m == 0) qls[rr * 64 + ln] = f2bf(v);
                else             sls[rr * 64 + ln] = v;
            }
        }
    }
    __syncthreads();

    int j = tid & 63, quarter = tid >> 6;
    const float invs = 0.17677669529663687f;  // 1/sqrt(32)
    float ps = 0.f, pss = 0.f;
    float* o2b = out2 + (size_t)b * D_ * G_;
    const int offs[13] = {0, 1, 2, 3, 4, 5, -1, -2, -3, -4, -5, -15, 15};
    for (int it = 0; it < 4; ++it) {
        int tl = it * 4 + quarter;         // 0..15
        int t = t0 + tl;
        float q = bf2f(qls[tl * 64 + j]);
        float lg[13], vv[13];
        #pragma unroll
        for (int n = 0; n < 13; ++n) {
            int ts = t + offs[n];
            bool ok = (ts >= 0) && (ts < D_);
            int ki = tl + 15 + offs[n];    // 0..45
            float kk = ok ? bf2f(kls[ki * 64 + j]) : 0.f;
            vv[n] = ok ? bf2f(vls[ki * 64 + j]) : 0.f;
            float p = q * kk;
            p += __shfl_xor(p, 16, 32);
            p += __shfl_xor(p, 8, 32);
            p += __shfl_xor(p, 4, 32);
            p += __shfl_xor(p, 2, 32);
            p += __shfl_xor(p, 1, 32);
            lg[n] = ok ? p * invs : -1e30f;
        }
        float m = lg[0];
        #pragma unroll
        for (int n = 1; n < 13; ++n) m = fmaxf(m, lg[n]);
        float den = 0.f, aggv = 0.f;
        #pragma unroll
        for (int n = 0; n < 13; ++n) {
            float e = expf(lg[n] - m);
            den += e;
            aggv += e * vv[n];
        }
        float o = aggv / den + sls[tl * 64 + j];
        o2b[(size_t)t * G_ + y * 64 + j] = o;
        ps += o; pss += o * o;
    }

    __syncthreads();
    float* red = (float*)raw;
    red[quarter * 64 + j] = ps;
    red[256 + quarter * 64 + j] = pss;
    __syncthreads();
    if (tid < 64) {
        float s = 0.f, ss = 0.f;
        #pragma unroll
        for (int qq = 0; qq < 4; ++qq) {
            s += red[qq * 64 + tid];
            ss += red[256 + qq * 64 + tid];
        }
        float* P = partials + ((size_t)b * 128 + (blk & 127)) * 256;
        P[y * 64 + tid] = s;
        P[128 + y * 64 + tid] = ss;
    }
}

// ------ BatchNorm apply (final layer -> d_out, f32; halved reduce) ------
__global__ __launch_bounds__(256) void bn_apply_kernel(
    const float* __restrict__ X, const float* __restrict__ partials,
    const float* __restrict__ gam, const float* __restrict__ bet,
    float* __restrict__ out)
{
    int chunk = blockIdx.x;   // 0..31 (64-row slices)
    int b = blockIdx.y;
    int tid = threadIdx.x;
    __shared__ float smu[G_], sinv[G_];
    __shared__ float sred[2][G_], ssred[2][G_];
    {
        int halfk = tid >> 7;          // 0/1
        int c = tid & 127;
        float s = 0.f, ss = 0.f;
        const float* P = partials + (size_t)b * 128 * 256;
        #pragma unroll 4
        for (int k = halfk * 64; k < halfk * 64 + 64; ++k) {
            s += P[k * 256 + c];
            ss += P[k * 256 + G_ + c];
        }
        sred[halfk][c] = s;
        ssred[halfk][c] = ss;
    }
    __syncthreads();
    if (tid < G_) {
        float S = sred[0][tid] + sred[1][tid];
        float SS = ssred[0][tid] + ssred[1][tid];
        float mu = S / D_;
        float var = SS / D_ - mu * mu;
        smu[tid] = mu;
        sinv[tid] = 1.0f / sqrtf(var + 1e-5f);
    }
    __syncthreads();

    const float4* base4 = (const float4*)(X + ((size_t)b * D_ + chunk * 64) * G_);
    int c4 = (tid & 31) * 4;
    float m0 = smu[c4], m1 = smu[c4 + 1], m2 = smu[c4 + 2], m3 = smu[c4 + 3];
    float i0 = sinv[c4] * gam[c4],     i1 = sinv[c4 + 1] * gam[c4 + 1];
    float i2 = sinv[c4 + 2] * gam[c4 + 2], i3 = sinv[c4 + 3] * gam[c4 + 3];
    float b0 = bet[c4], b1 = bet[c4 + 1], b2 = bet[c4 + 2], b3 = bet[c4 + 3];
    #pragma unroll
    for (int p = 0; p < 8; ++p) {
        float4 v = base4[p * 256 + tid];
        float4 y;
        y.x = (v.x - m0) * i0 + b0;
        y.y = (v.y - m1) * i1 + b1;
        y.z = (v.z - m2) * i2 + b2;
        y.w = (v.w - m3) * i3 + b3;
        y.x = (y.x > 0.f) ? y.x : 0.01f * y.x;
        y.y = (y.y > 0.f) ? y.y : 0.01f * y.y;
        y.z = (y.z > 0.f) ? y.z : 0.01f * y.z;
        y.w = (y.w > 0.f) ? y.w : 0.01f * y.w;
        float4* ob = (float4*)(out + ((size_t)b * D_ + chunk * 64) * G_);
        ob[p * 256 + tid] = y;
    }
}

extern "C" void kernel_launch(void* const* d_in, const int* in_sizes, int n_in,
                              void* d_out, int out_size, void* d_ws, size_t ws_size,
                              hipStream_t stream)
{
    (void)in_sizes; (void)n_in; (void)out_size; (void)ws_size;
    const float* x      = (const float*)d_in[0];
    const float* fe_w   = (const float*)d_in[3];
    const float* fe_b   = (const float*)d_in[4];
    const float* ln_g   = (const float*)d_in[5];
    const float* ln_b   = (const float*)d_in[6];
    const float* w_rel  = (const float*)d_in[7];   // [2][4][128][128]
    const float* w_root = (const float*)d_in[8];   // [2][128][128]
    const float* rgcn_b = (const float*)d_in[9];   // [2][128]
    const float* wq  = (const float*)d_in[10];
    const float* bq  = (const float*)d_in[11];
    const float* wk  = (const float*)d_in[12];
    const float* bk  = (const float*)d_in[13];
    const float* wv  = (const float*)d_in[14];
    const float* bv  = (const float*)d_in[15];
    const float* wsk = (const float*)d_in[16];
    const float* bsk = (const float*)d_in[17];
    const float* bn_g = (const float*)d_in[18];
    const float* bn_b = (const float*)d_in[19];

    float* ws   = (float*)d_ws;
    float* out2 = ws;                                  // [8192][128] f32
    float* partials = out2 + (size_t)NODES * G_;       // [4][128][256] f32
    unsigned short* nf_bf  = (unsigned short*)(partials + 4 * 128 * 256);
    unsigned short* nf1_bf = nf_bf + (size_t)NODES * G_;
    unsigned short* wbf    = nf1_bf + (size_t)NODES * G_;   // 16 x [128][128]

    WconvArgs wa;
    for (int l = 0; l < 2; ++l) {
        for (int r = 0; r < 4; ++r) {
            wa.src[l * 8 + r] = w_rel + ((size_t)l * 4 + r) * G_ * G_;
            wa.add[l * 8 + r] = (r == 0) ? (w_root + (size_t)l * G_ * G_) : nullptr;
        }
        wa.src[l * 8 + 4] = wq  + (size_t)l * G_ * G_; wa.add[l * 8 + 4] = nullptr;
        wa.src[l * 8 + 5] = wk  + (size_t)l * G_ * G_; wa.add[l * 8 + 5] = nullptr;
        wa.src[l * 8 + 6] = wv  + (size_t)l * G_ * G_; wa.add[l * 8 + 6] = nullptr;
        wa.src[l * 8 + 7] = wsk + (size_t)l * G_ * G_; wa.add[l * 8 + 7] = nullptr;
    }

    pool_fc_ln_kernel<<<NODES, 192, 0, stream>>>(
        x, fe_w, fe_b, ln_g, ln_b, nf_bf, wa, wbf);

    // ---- layer 0 ----
    rgcn_fused_kernel<false><<<dim3(512, 2), 256, 0, stream>>>(
        nf_bf, nullptr, nullptr, nullptr, nullptr,
        wbf, rgcn_b, nf1_bf);
    qkvs_attn_kernel<<<dim3(512, 2), 256, 0, stream>>>(
        nf1_bf, wbf + (size_t)4 * 16384,
        bq, bk, bv, bsk, out2, partials);

    // ---- layer 1 (BN of layer-0 folded into rgcn staging) ----
    rgcn_fused_kernel<true><<<dim3(512, 2), 256, 0, stream>>>(
        nullptr, out2, partials, bn_g, bn_b,
        wbf + (size_t)8 * 16384, rgcn_b + G_, nf1_bf);
    qkvs_attn_kernel<<<dim3(512, 2), 256, 0, stream>>>(
        nf1_bf, wbf + (size_t)12 * 16384,
        bq + G_, bk + G_, bv + G_, bsk + G_, out2, partials);

    bn_apply_kernel<<<dim3(32, 4), 256, 0, stream>>>(
        out2, partials, bn_g + G_, bn_b + G_, (float*)d_out);
}

// Round 17
// 209.211 us; speedup vs baseline: 2.9974x; 1.0237x over previous
//
#include <hip/hip_runtime.h>
#include <hip/hip_bf16.h>

#define B_ 4
#define D_ 2048
#define HWS 64
#define C_ 192
#define G_ 128
#define NODES (B_*D_)   // 8192
#define R_ 16           // central rows per fused block
#define HALO_ROWS 48    // t0-15 .. t0+32 staged

typedef short bf8_t  __attribute__((ext_vector_type(8)));   // 8 bf16 (4 VGPR)
typedef float f32x4_t __attribute__((ext_vector_type(4)));

__device__ inline unsigned short f2bf(float f) {
    unsigned int u = __builtin_bit_cast(unsigned int, f);
    unsigned int r = (u + 0x7fffu + ((u >> 16) & 1u)) >> 16;   // RNE
    return (unsigned short)r;
}
__device__ inline float bf2f(unsigned short h) {
    unsigned int u = ((unsigned int)h) << 16;
    return __builtin_bit_cast(float, u);
}

// XCD-aware bijective swizzle for 512-block x-dim (8 XCDs, 512%8==0):
// same-XCD blocks process consecutive chunks -> halo rows L2-co-resident.
__device__ inline int xcd_swz(int x) { return (x & 7) * 64 + (x >> 3); }

struct WconvArgs {
    const float* src[16];
    const float* add[16];   // null or w_root slice (folded into slot 0)
};

// ---------------- K1: pool + FC + LayerNorm  (+ folded weight conv) -----
// PROVEN r16 (214 us champion) — unchanged.
__global__ __launch_bounds__(192) void pool_fc_ln_kernel(
    const float* __restrict__ x, const float* __restrict__ W,
    const float* __restrict__ bias, const float* __restrict__ gam,
    const float* __restrict__ bet, unsigned short* __restrict__ nf,
    WconvArgs wa, unsigned short* __restrict__ wbf)
{
    int u = blockIdx.x;            // 0..8191 (= b*2048 + t)
    int tid = threadIdx.x;         // 0..191
    __shared__ float feat[C_];
    __shared__ float4 red4[4][48];
    __shared__ float red[4];
    __shared__ float stats[2];

    const float4* xb4 = (const float4*)(x + (size_t)u * (HWS * C_)); // 48 f4/row
    int cg = tid % 48;
    int rg = tid / 48;             // 0..3
    float4 a = make_float4(0.f, 0.f, 0.f, 0.f);
    #pragma unroll
    for (int s = 0; s < HWS; s += 4) {
        float4 v = xb4[(size_t)(s + rg) * 48 + cg];
        a.x += v.x; a.y += v.y; a.z += v.z; a.w += v.w;
    }
    red4[rg][cg] = a;
    __syncthreads();
    if (rg == 0) {
        float4 b0 = red4[0][cg], b1 = red4[1][cg], b2 = red4[2][cg], b3 = red4[3][cg];
        feat[cg * 4 + 0] = (b0.x + b1.x + b2.x + b3.x) * (1.0f / HWS);
        feat[cg * 4 + 1] = (b0.y + b1.y + b2.y + b3.y) * (1.0f / HWS);
        feat[cg * 4 + 2] = (b0.z + b1.z + b2.z + b3.z) * (1.0f / HWS);
        feat[cg * 4 + 3] = (b0.w + b1.w + b2.w + b3.w) * (1.0f / HWS);
    }
    __syncthreads();

    float h = 0.f;
    if (tid < G_) {
        h = bias[tid];
        #pragma unroll 4
        for (int c = 0; c < C_; ++c) h += feat[c] * W[c * G_ + tid];
    }
    float s1 = (tid < G_) ? h : 0.f;
    float s2 = (tid < G_) ? h * h : 0.f;
    #pragma unroll
    for (int off = 32; off >= 1; off >>= 1) {
        s1 += __shfl_xor(s1, off, 64);
        s2 += __shfl_xor(s2, off, 64);
    }
    int wid = tid >> 6;
    if ((tid & 63) == 0 && wid < 2) { red[wid] = s1; red[2 + wid] = s2; }
    __syncthreads();
    if (tid == 0) {
        float S = red[0] + red[1];
        float SS = red[2] + red[3];
        float mu = S / G_;
        float var = SS / G_ - mu * mu;
        stats[0] = mu;
        stats[1] = 1.0f / sqrtf(var + 1e-5f);
    }
    __syncthreads();
    if (tid < G_) {
        float v = (h - stats[0]) * stats[1] * gam[tid] + bet[tid];
        nf[(size_t)u * G_ + tid] = f2bf(v);
    }

    // ---- folded weight conversion (same math as old wconv_kernel) ----
    if (u < 2048 && tid < 128) {
        int idx = u * 128 + tid;           // 0..262143
        int m = idx >> 14;                 // 0..15
        int within = idx & 16383;          // n*128 + k
        int n = within >> 7, k = within & 127;
        float v = wa.src[m][k * G_ + n];
        if (wa.add[m]) v += wa.add[m][k * G_ + n];
        wbf[(size_t)m * 16384 + within] = f2bf(v);
    }
}

// ------ fused RGCN: [optional BN+lReLU on input] + aggregate + GEMM -----
// VERBATIM r11/r16 body; blockIdx.x XCD-swizzled.
template <bool BNIN>
__global__ __launch_bounds__(256) void rgcn_fused_kernel(
    const unsigned short* __restrict__ nf, const float* __restrict__ xin,
    const float* __restrict__ partials, const float* __restrict__ gam,
    const float* __restrict__ bet,
    const unsigned short* __restrict__ wt,   // 4 mats [128 n][128 k] bf16
    const float* __restrict__ rb,
    unsigned short* __restrict__ out)
{
    __shared__ char raw[HALO_ROWS * 256];   // 12 KB halo (swizzled)
    __shared__ char agg[R_ * 1024];         // 16 KB: [row][rel][128k] (swizzled)
    __shared__ float smu[G_], sivg[G_], sbet[G_];
    __shared__ float sred[2][G_], ssred[2][G_];
    int blk = xcd_swz(blockIdx.x);
    int b = blk >> 7;
    int t0 = (blk & 127) * R_;
    int tid = threadIdx.x;

    if constexpr (BNIN) {
        int halfk = tid >> 7;          // 0/1
        int c = tid & 127;
        float s = 0.f, ss = 0.f;
        const float* P = partials + (size_t)b * 128 * 256;
        #pragma unroll 4
        for (int k = halfk * 64; k < halfk * 64 + 64; ++k) {
            s += P[k * 256 + c];
            ss += P[k * 256 + G_ + c];
        }
        sred[halfk][c] = s;
        ssred[halfk][c] = ss;
        __syncthreads();
        if (tid < G_) {
            float S = sred[0][tid] + sred[1][tid];
            float SS = ssred[0][tid] + ssred[1][tid];
            float mu = S / D_;
            float var = SS / D_ - mu * mu;
            float inv = 1.0f / sqrtf(var + 1e-5f);
            smu[tid] = mu;
            sivg[tid] = inv * gam[tid];
            sbet[tid] = bet[tid];
        }
        __syncthreads();
        const float* xb = xin + (size_t)b * D_ * G_;
        #pragma unroll
        for (int p = 0; p < 3; ++p) {
            int task = tid + p * 256;
            int i = task >> 4, c16 = task & 15;
            int t = t0 - 15 + i;
            bf8_t v8 = {0, 0, 0, 0, 0, 0, 0, 0};
            if (t >= 0 && t < D_) {
                const float* vp = xb + (size_t)t * G_ + c16 * 8;
                #pragma unroll
                for (int e = 0; e < 8; ++e) {
                    int c = c16 * 8 + e;
                    float yv = (vp[e] - smu[c]) * sivg[c] + sbet[c];
                    yv = (yv > 0.f) ? yv : 0.01f * yv;
                    v8[e] = (short)f2bf(yv);
                }
            }
            *(bf8_t*)(raw + ((i * 256 + c16 * 16) ^ ((i & 7) << 4))) = v8;
        }
    } else {
        const unsigned short* src = nf + (size_t)b * D_ * G_;
        #pragma unroll
        for (int p = 0; p < 3; ++p) {
            int task = tid + p * 256;        // 768 tasks = 48 rows x 16 chunks
            int i = task >> 4, c16 = task & 15;
            int t = t0 - 15 + i;
            bf8_t v = {0, 0, 0, 0, 0, 0, 0, 0};
            if (t >= 0 && t < D_) v = *(const bf8_t*)(src + (size_t)t * G_ + c16 * 8);
            *(bf8_t*)(raw + ((i * 256 + c16 * 16) ^ ((i & 7) << 4))) = v;
        }
    }
    __syncthreads();

    #pragma unroll
    for (int p = 0; p < 4; ++p) {
        int task = tid + p * 256;
        int c16 = task & 15, rel = (task >> 4) & 3, row = task >> 6;   // row 0..15
        int t = t0 + row;
        int ctr = row + 15;
        float s[8] = {0.f,0.f,0.f,0.f,0.f,0.f,0.f,0.f};
        float scale = 1.f;
        if (rel == 0) {
            bf8_t v = *(const bf8_t*)(raw + ((ctr * 256 + c16 * 16) ^ ((ctr & 7) << 4)));
            #pragma unroll
            for (int e = 0; e < 8; ++e) s[e] = bf2f((unsigned short)v[e]);
        } else if (rel == 1) {
            #pragma unroll
            for (int o = 1; o <= 5; ++o) if (t + o < D_) {
                int i = ctr + o;
                bf8_t v = *(const bf8_t*)(raw + ((i * 256 + c16 * 16) ^ ((i & 7) << 4)));
                #pragma unroll
                for (int e = 0; e < 8; ++e) s[e] += bf2f((unsigned short)v[e]);
            }
            scale = 1.f / (float)max(min(5, D_ - 1 - t), 1);
        } else if (rel == 2) {
            #pragma unroll
            for (int o = 1; o <= 5; ++o) if (t - o >= 0) {
                int i = ctr - o;
                bf8_t v = *(const bf8_t*)(raw + ((i * 256 + c16 * 16) ^ ((i & 7) << 4)));
                #pragma unroll
                for (int e = 0; e < 8; ++e) s[e] += bf2f((unsigned short)v[e]);
            }
            scale = 1.f / (float)max(min(5, t), 1);
        } else {
            int cnt = 0;
            if (t >= 15) {
                int i = ctr - 15;
                bf8_t v = *(const bf8_t*)(raw + ((i * 256 + c16 * 16) ^ ((i & 7) << 4)));
                #pragma unroll
                for (int e = 0; e < 8; ++e) s[e] += bf2f((unsigned short)v[e]);
                cnt++;
            }
            if (t + 15 < D_) {
                int i = ctr + 15;
                bf8_t v = *(const bf8_t*)(raw + ((i * 256 + c16 * 16) ^ ((i & 7) << 4)));
                #pragma unroll
                for (int e = 0; e < 8; ++e) s[e] += bf2f((unsigned short)v[e]);
                cnt++;
            }
            scale = 1.f / (float)max(cnt, 1);
        }
        bf8_t o8;
        #pragma unroll
        for (int e = 0; e < 8; ++e) o8[e] = (short)f2bf(s[e] * scale);
        *(bf8_t*)(agg + ((row * 1024 + rel * 256 + c16 * 16) ^ ((row & 7) << 4))) = o8;
    }
    __syncthreads();

    int l = tid & 63, wv = tid >> 6;
    int l15 = l & 15, kgrp = l >> 4;
    int col16 = blockIdx.y * 4 + wv;
    f32x4_t acc = (f32x4_t){0.f, 0.f, 0.f, 0.f};

    for (int ks = 0; ks < 16; ++ks) {
        int rel = ks >> 2, kk = ks & 3;
        bf8_t a = *(const bf8_t*)(agg +
            ((l15 * 1024 + rel * 256 + kk * 64 + kgrp * 16) ^ ((l15 & 7) << 4)));
        bf8_t bf = *(const bf8_t*)(wt + rel * 16384 +
            (size_t)(col16 * 16 + l15) * G_ + kk * 32 + kgrp * 8);
        acc = __builtin_amdgcn_mfma_f32_16x16x32_bf16(a, bf, acc, 0, 0, 0);
    }

    unsigned short* outb = out + (size_t)b * D_ * G_;
    int rbase = t0 + kgrp * 4;
    int col = col16 * 16 + l15;
    float rbv = rb[col];
    #pragma unroll
    for (int j = 0; j < 4; ++j)
        outb[(size_t)(rbase + j) * G_ + col] = f2bf(acc[j] + rbv);
}

// ---- helper: stage 48 halo rows of a bf16 [D][128] (qkvs staging) ------
__device__ inline void stage_halo48(const unsigned short* __restrict__ src,
                                    int t0, char* raw, int tid)
{
    #pragma unroll
    for (int p = 0; p < 3; ++p) {
        int task = tid + p * 256;        // 768 tasks = 48 rows x 16 chunks
        int i = task >> 4, c16 = task & 15;
        int t = t0 - 15 + i;
        bf8_t v = {0, 0, 0, 0, 0, 0, 0, 0};
        if (t >= 0 && t < D_) v = *(const bf8_t*)(src + (size_t)t * G_ + c16 * 8);
        *(bf8_t*)(raw + ((i * 256 + c16 * 16) ^ ((i & 7) << 4))) = v;
    }
}

// ------ fused QKVS GEMM + attention + BN partials, COL-SPLIT ------------
// VERBATIM r11/r16 body; blockIdx.x XCD-swizzled.
__global__ __launch_bounds__(256) void qkvs_attn_kernel(
    const unsigned short* __restrict__ nf1,
    const unsigned short* __restrict__ wt,  // 4 mats: q,k,v,skip
    const float* __restrict__ bq, const float* __restrict__ bk,
    const float* __restrict__ bv, const float* __restrict__ bsk,
    float* __restrict__ out2, float* __restrict__ partials)
{
    __shared__ char raw[HALO_ROWS * 256];            // 12 KB (swizzled halo)
    __shared__ unsigned short kls[HALO_ROWS * 64];   // 6 KB
    __shared__ unsigned short vls[HALO_ROWS * 64];   // 6 KB
    __shared__ unsigned short qls[R_ * 64];          // 2 KB
    __shared__ float sls[R_ * 64];                   // 4 KB
    int blk = xcd_swz(blockIdx.x);
    int tid = threadIdx.x;
    int b = blk >> 7, t0 = (blk & 127) * R_;
    int y = blockIdx.y;

    stage_halo48(nf1 + (size_t)b * D_ * G_, t0, raw, tid);
    __syncthreads();

    int l = tid & 63, wvid = tid >> 6;
    int l15 = l & 15, kgrp = l >> 4;
    #pragma unroll
    for (int i = 0; i < 2; ++i) {
        int job = wvid + i * 4;
        int m, frag;
        if (job < 3)      { m = 1; frag = job; }        // K
        else if (job < 6) { m = 2; frag = job - 3; }    // V
        else if (job == 6){ m = 0; frag = 0; }          // Q
        else              { m = 3; frag = 0; }          // S
        bool halo = (m == 1) | (m == 2);
        int rawrow = halo ? (frag * 16 + l15) : (15 + l15);
        const unsigned short* wm = wt + (size_t)m * 16384;
        const float* bias = (m == 0) ? bq : (m == 1) ? bk : (m == 2) ? bv : bsk;

        bf8_t a[4];
        #pragma unroll
        for (int kc = 0; kc < 4; ++kc)
            a[kc] = *(const bf8_t*)(raw +
                ((rawrow * 256 + kc * 64 + kgrp * 16) ^ ((rawrow & 7) << 4)));
        f32x4_t acc[4];
        #pragma unroll
        for (int n = 0; n < 4; ++n) acc[n] = (f32x4_t){0.f, 0.f, 0.f, 0.f};
        #pragma unroll
        for (int kc = 0; kc < 4; ++kc) {
            #pragma unroll
            for (int n = 0; n < 4; ++n) {
                int col = y * 64 + n * 16 + l15;
                bf8_t bf = *(const bf8_t*)(wm +
                    (size_t)col * G_ + kc * 32 + kgrp * 8);
                acc[n] = __builtin_amdgcn_mfma_f32_16x16x32_bf16(a[kc], bf, acc[n], 0, 0, 0);
            }
        }
        int r0 = frag * 16 + kgrp * 4;
        #pragma unroll
        for (int n = 0; n < 4; ++n) {
            int ln = n * 16 + l15;              // local col 0..63
            float bb = bias[y * 64 + ln];
            #pragma unroll
            for (int j = 0; j < 4; ++j) {
                float v = acc[n][j] + bb;
                int rr = r0 + j;
                if (m == 1)      kls[rr * 64 + ln] = f2bf(v);
                else if (m == 2) vls[rr * 64 + ln] = f2bf(v);
                else if (m == 0) qls[rr * 64 + ln] = f2bf(v);
                else             sls[rr * 64 + ln] = v;
            }
        }
    }
    __syncthreads();

    int j = tid & 63, quarter = tid >> 6;
    const float invs = 0.17677669529663687f;  // 1/sqrt(32)
    float ps = 0.f, pss = 0.f;
    float* o2b = out2 + (size_t)b * D_ * G_;
    const int offs[13] = {0, 1, 2, 3, 4, 5, -1, -2, -3, -4, -5, -15, 15};
    for (int it = 0; it < 4; ++it) {
        int tl = it * 4 + quarter;         // 0..15
        int t = t0 + tl;
        float q = bf2f(qls[tl * 64 + j]);
        float lg[13], vv[13];
        #pragma unroll
        for (int n = 0; n < 13; ++n) {
            int ts = t + offs[n];
            bool ok = (ts >= 0) && (ts < D_);
            int ki = tl + 15 + offs[n];    // 0..45
            float kk = ok ? bf2f(kls[ki * 64 + j]) : 0.f;
            vv[n] = ok ? bf2f(vls[ki * 64 + j]) : 0.f;
            float p = q * kk;
            p += __shfl_xor(p, 16, 32);
            p += __shfl_xor(p, 8, 32);
            p += __shfl_xor(p, 4, 32);
            p += __shfl_xor(p, 2, 32);
            p += __shfl_xor(p, 1, 32);
            lg[n] = ok ? p * invs : -1e30f;
        }
        float m = lg[0];
        #pragma unroll
        for (int n = 1; n < 13; ++n) m = fmaxf(m, lg[n]);
        float den = 0.f, aggv = 0.f;
        #pragma unroll
        for (int n = 0; n < 13; ++n) {
            float e = expf(lg[n] - m);
            den += e;
            aggv += e * vv[n];
        }
        float o = aggv / den + sls[tl * 64 + j];
        o2b[(size_t)t * G_ + y * 64 + j] = o;
        ps += o; pss += o * o;
    }

    __syncthreads();
    float* red = (float*)raw;
    red[quarter * 64 + j] = ps;
    red[256 + quarter * 64 + j] = pss;
    __syncthreads();
    if (tid < 64) {
        float s = 0.f, ss = 0.f;
        #pragma unroll
        for (int qq = 0; qq < 4; ++qq) {
            s += red[qq * 64 + tid];
            ss += red[256 + qq * 64 + tid];
        }
        float* P = partials + ((size_t)b * 128 + (blk & 127)) * 256;
        P[y * 64 + tid] = s;
        P[128 + y * 64 + tid] = ss;
    }
}

// ------ BatchNorm apply (final -> d_out, f32): 512 blocks x 16 rows -----
// PROVEN body (r14 bn_final_phase, ran at absmax 0.03125).
__global__ __launch_bounds__(256) void bn_apply_kernel(
    const float* __restrict__ X, const float* __restrict__ partials,
    const float* __restrict__ gam, const float* __restrict__ bet,
    float* __restrict__ out)
{
    int blk = blockIdx.x;       // 0..511
    int b = blk >> 7;           // 0..3
    int chunk = blk & 127;      // 16-row slice
    int tid = threadIdx.x;
    __shared__ float smu[G_], sinv[G_];
    __shared__ float sred[2][G_], ssred[2][G_];
    {
        int halfk = tid >> 7;
        int c = tid & 127;
        float s = 0.f, ss = 0.f;
        const float* P = partials + (size_t)b * 128 * 256;
        #pragma unroll 4
        for (int k = halfk * 64; k < halfk * 64 + 64; ++k) {
            s += P[k * 256 + c];
            ss += P[k * 256 + G_ + c];
        }
        sred[halfk][c] = s;
        ssred[halfk][c] = ss;
    }
    __syncthreads();
    if (tid < G_) {
        float S = sred[0][tid] + sred[1][tid];
        float SS = ssred[0][tid] + ssred[1][tid];
        float mu = S / D_;
        float var = SS / D_ - mu * mu;
        smu[tid] = mu;
        sinv[tid] = 1.0f / sqrtf(var + 1e-5f);
    }
    __syncthreads();

    const float4* base4 = (const float4*)(X + ((size_t)b * D_ + chunk * 16) * G_);
    float4* ob4 = (float4*)(out + ((size_t)b * D_ + chunk * 16) * G_);
    int c4 = (tid & 31) * 4;
    float m0 = smu[c4], m1 = smu[c4 + 1], m2 = smu[c4 + 2], m3 = smu[c4 + 3];
    float i0 = sinv[c4] * gam[c4],     i1 = sinv[c4 + 1] * gam[c4 + 1];
    float i2 = sinv[c4 + 2] * gam[c4 + 2], i3 = sinv[c4 + 3] * gam[c4 + 3];
    float b0 = bet[c4], b1 = bet[c4 + 1], b2 = bet[c4 + 2], b3 = bet[c4 + 3];
    #pragma unroll
    for (int p = 0; p < 2; ++p) {
        float4 v = base4[p * 256 + tid];
        float4 y;
        y.x = (v.x - m0) * i0 + b0;
        y.y = (v.y - m1) * i1 + b1;
        y.z = (v.z - m2) * i2 + b2;
        y.w = (v.w - m3) * i3 + b3;
        y.x = (y.x > 0.f) ? y.x : 0.01f * y.x;
        y.y = (y.y > 0.f) ? y.y : 0.01f * y.y;
        y.z = (y.z > 0.f) ? y.z : 0.01f * y.z;
        y.w = (y.w > 0.f) ? y.w : 0.01f * y.w;
        ob4[p * 256 + tid] = y;
    }
}

extern "C" void kernel_launch(void* const* d_in, const int* in_sizes, int n_in,
                              void* d_out, int out_size, void* d_ws, size_t ws_size,
                              hipStream_t stream)
{
    (void)in_sizes; (void)n_in; (void)out_size; (void)ws_size;
    const float* x      = (const float*)d_in[0];
    const float* fe_w   = (const float*)d_in[3];
    const float* fe_b   = (const float*)d_in[4];
    const float* ln_g   = (const float*)d_in[5];
    const float* ln_b   = (const float*)d_in[6];
    const float* w_rel  = (const float*)d_in[7];   // [2][4][128][128]
    const float* w_root = (const float*)d_in[8];   // [2][128][128]
    const float* rgcn_b = (const float*)d_in[9];   // [2][128]
    const float* wq  = (const float*)d_in[10];
    const float* bq  = (const float*)d_in[11];
    const float* wk  = (const float*)d_in[12];
    const float* bk  = (const float*)d_in[13];
    const float* wv  = (const float*)d_in[14];
    const float* bv  = (const float*)d_in[15];
    const float* wsk = (const float*)d_in[16];
    const float* bsk = (const float*)d_in[17];
    const float* bn_g = (const float*)d_in[18];
    const float* bn_b = (const float*)d_in[19];

    float* ws   = (float*)d_ws;
    float* out2 = ws;                                  // [8192][128] f32
    float* partials = out2 + (size_t)NODES * G_;       // [4][128][256] f32
    unsigned short* nf_bf  = (unsigned short*)(partials + 4 * 128 * 256);
    unsigned short* nf1_bf = nf_bf + (size_t)NODES * G_;
    unsigned short* wbf    = nf1_bf + (size_t)NODES * G_;   // 16 x [128][128]

    WconvArgs wa;
    for (int l = 0; l < 2; ++l) {
        for (int r = 0; r < 4; ++r) {
            wa.src[l * 8 + r] = w_rel + ((size_t)l * 4 + r) * G_ * G_;
            wa.add[l * 8 + r] = (r == 0) ? (w_root + (size_t)l * G_ * G_) : nullptr;
        }
        wa.src[l * 8 + 4] = wq  + (size_t)l * G_ * G_; wa.add[l * 8 + 4] = nullptr;
        wa.src[l * 8 + 5] = wk  + (size_t)l * G_ * G_; wa.add[l * 8 + 5] = nullptr;
        wa.src[l * 8 + 6] = wv  + (size_t)l * G_ * G_; wa.add[l * 8 + 6] = nullptr;
        wa.src[l * 8 + 7] = wsk + (size_t)l * G_ * G_; wa.add[l * 8 + 7] = nullptr;
    }

    pool_fc_ln_kernel<<<NODES, 192, 0, stream>>>(
        x, fe_w, fe_b, ln_g, ln_b, nf_bf, wa, wbf);

    // ---- layer 0 ----
    rgcn_fused_kernel<false><<<dim3(512, 2), 256, 0, stream>>>(
        nf_bf, nullptr, nullptr, nullptr, nullptr,
        wbf, rgcn_b, nf1_bf);
    qkvs_attn_kernel<<<dim3(512, 2), 256, 0, stream>>>(
        nf1_bf, wbf + (size_t)4 * 16384,
        bq, bk, bv, bsk, out2, partials);

    // ---- layer 1 (BN of layer-0 folded into rgcn staging) ----
    rgcn_fused_kernel<true><<<dim3(512, 2), 256, 0, stream>>>(
        nullptr, out2, partials, bn_g, bn_b,
        wbf + (size_t)8 * 16384, rgcn_b + G_, nf1_bf);
    qkvs_attn_kernel<<<dim3(512, 2), 256, 0, stream>>>(
        nf1_bf, wbf + (size_t)12 * 16384,
        bq + G_, bk + G_, bv + G_, bsk + G_, out2, partials);

    bn_apply_kernel<<<512, 256, 0, stream>>>(
        out2, partials, bn_g + G_, bn_b + G_, (float*)d_out);
}

// Round 18
// 207.646 us; speedup vs baseline: 3.0200x; 1.0075x over previous
//
#include <hip/hip_runtime.h>
#include <hip/hip_bf16.h>

#define B_ 4
#define D_ 2048
#define HWS 64
#define C_ 192
#define G_ 128
#define NODES (B_*D_)   // 8192
#define R_ 16           // central rows per fused block
#define HALO_ROWS 48    // t0-15 .. t0+32 staged

typedef short bf8_t  __attribute__((ext_vector_type(8)));   // 8 bf16 (4 VGPR)
typedef float f32x4_t __attribute__((ext_vector_type(4)));

__device__ inline unsigned short f2bf(float f) {
    unsigned int u = __builtin_bit_cast(unsigned int, f);
    unsigned int r = (u + 0x7fffu + ((u >> 16) & 1u)) >> 16;   // RNE
    return (unsigned short)r;
}
__device__ inline float bf2f(unsigned short h) {
    unsigned int u = ((unsigned int)h) << 16;
    return __builtin_bit_cast(float, u);
}

// XCD-aware bijective swizzle for 512-block x-dim (8 XCDs, 512%8==0).
__device__ inline int xcd_swz(int x) { return (x & 7) * 64 + (x >> 3); }

struct WconvArgs {
    const float* src[16];
    const float* add[16];   // null or w_root slice (folded into slot 0)
};

// ---------------- K1: pool + FC + LayerNorm  (+ folded weight conv) -----
// PROVEN r16/r17 — unchanged.
__global__ __launch_bounds__(192) void pool_fc_ln_kernel(
    const float* __restrict__ x, const float* __restrict__ W,
    const float* __restrict__ bias, const float* __restrict__ gam,
    const float* __restrict__ bet, unsigned short* __restrict__ nf,
    WconvArgs wa, unsigned short* __restrict__ wbf)
{
    int u = blockIdx.x;            // 0..8191 (= b*2048 + t)
    int tid = threadIdx.x;         // 0..191
    __shared__ float feat[C_];
    __shared__ float4 red4[4][48];
    __shared__ float red[4];
    __shared__ float stats[2];

    const float4* xb4 = (const float4*)(x + (size_t)u * (HWS * C_)); // 48 f4/row
    int cg = tid % 48;
    int rg = tid / 48;             // 0..3
    float4 a = make_float4(0.f, 0.f, 0.f, 0.f);
    #pragma unroll
    for (int s = 0; s < HWS; s += 4) {
        float4 v = xb4[(size_t)(s + rg) * 48 + cg];
        a.x += v.x; a.y += v.y; a.z += v.z; a.w += v.w;
    }
    red4[rg][cg] = a;
    __syncthreads();
    if (rg == 0) {
        float4 b0 = red4[0][cg], b1 = red4[1][cg], b2 = red4[2][cg], b3 = red4[3][cg];
        feat[cg * 4 + 0] = (b0.x + b1.x + b2.x + b3.x) * (1.0f / HWS);
        feat[cg * 4 + 1] = (b0.y + b1.y + b2.y + b3.y) * (1.0f / HWS);
        feat[cg * 4 + 2] = (b0.z + b1.z + b2.z + b3.z) * (1.0f / HWS);
        feat[cg * 4 + 3] = (b0.w + b1.w + b2.w + b3.w) * (1.0f / HWS);
    }
    __syncthreads();

    float h = 0.f;
    if (tid < G_) {
        h = bias[tid];
        #pragma unroll 4
        for (int c = 0; c < C_; ++c) h += feat[c] * W[c * G_ + tid];
    }
    float s1 = (tid < G_) ? h : 0.f;
    float s2 = (tid < G_) ? h * h : 0.f;
    #pragma unroll
    for (int off = 32; off >= 1; off >>= 1) {
        s1 += __shfl_xor(s1, off, 64);
        s2 += __shfl_xor(s2, off, 64);
    }
    int wid = tid >> 6;
    if ((tid & 63) == 0 && wid < 2) { red[wid] = s1; red[2 + wid] = s2; }
    __syncthreads();
    if (tid == 0) {
        float S = red[0] + red[1];
        float SS = red[2] + red[3];
        float mu = S / G_;
        float var = SS / G_ - mu * mu;
        stats[0] = mu;
        stats[1] = 1.0f / sqrtf(var + 1e-5f);
    }
    __syncthreads();
    if (tid < G_) {
        float v = (h - stats[0]) * stats[1] * gam[tid] + bet[tid];
        nf[(size_t)u * G_ + tid] = f2bf(v);
    }

    if (u < 2048 && tid < 128) {
        int idx = u * 128 + tid;           // 0..262143
        int m = idx >> 14;                 // 0..15
        int within = idx & 16383;          // n*128 + k
        int n = within >> 7, k = within & 127;
        float v = wa.src[m][k * G_ + n];
        if (wa.add[m]) v += wa.add[m][k * G_ + n];
        wbf[(size_t)m * 16384 + within] = f2bf(v);
    }
}

// ------ fused RGCN, 512-thread merged-y: stage/agg ONCE, 8 col16s -------
// Per-element math bit-identical to r17; work redistributed over 8 waves.
template <bool BNIN>
__global__ __launch_bounds__(512, 4) void rgcn_fused_kernel(
    const unsigned short* __restrict__ nf, const float* __restrict__ xin,
    const float* __restrict__ partials, const float* __restrict__ gam,
    const float* __restrict__ bet,
    const unsigned short* __restrict__ wt,   // 4 mats [128 n][128 k] bf16
    const float* __restrict__ rb,
    unsigned short* __restrict__ out)
{
    __shared__ char raw[HALO_ROWS * 256];   // 12 KB halo (swizzled)
    __shared__ char agg[R_ * 1024];         // 16 KB
    __shared__ float smu[G_], sivg[G_], sbet[G_];
    __shared__ float sred[2][G_], ssred[2][G_];
    int blk = xcd_swz(blockIdx.x);
    int b = blk >> 7;
    int t0 = (blk & 127) * R_;
    int tid = threadIdx.x;          // 0..511

    if constexpr (BNIN) {
        // BN stats: verbatim r16 path (threads 0..255 only -> bit-identical)
        if (tid < 256) {
            int halfk = tid >> 7;
            int c = tid & 127;
            float s = 0.f, ss = 0.f;
            const float* P = partials + (size_t)b * 128 * 256;
            #pragma unroll 4
            for (int k = halfk * 64; k < halfk * 64 + 64; ++k) {
                s += P[k * 256 + c];
                ss += P[k * 256 + G_ + c];
            }
            sred[halfk][c] = s;
            ssred[halfk][c] = ss;
        }
        __syncthreads();
        if (tid < G_) {
            float S = sred[0][tid] + sred[1][tid];
            float SS = ssred[0][tid] + ssred[1][tid];
            float mu = S / D_;
            float var = SS / D_ - mu * mu;
            float inv = 1.0f / sqrtf(var + 1e-5f);
            smu[tid] = mu;
            sivg[tid] = inv * gam[tid];
            sbet[tid] = bet[tid];
        }
        __syncthreads();
        const float* xb = xin + (size_t)b * D_ * G_;
        #pragma unroll
        for (int p = 0; p < 2; ++p) {
            int task = tid + p * 512;
            if (task < HALO_ROWS * 16) {
                int i = task >> 4, c16 = task & 15;
                int t = t0 - 15 + i;
                bf8_t v8 = {0, 0, 0, 0, 0, 0, 0, 0};
                if (t >= 0 && t < D_) {
                    const float* vp = xb + (size_t)t * G_ + c16 * 8;
                    #pragma unroll
                    for (int e = 0; e < 8; ++e) {
                        int c = c16 * 8 + e;
                        float yv = (vp[e] - smu[c]) * sivg[c] + sbet[c];
                        yv = (yv > 0.f) ? yv : 0.01f * yv;
                        v8[e] = (short)f2bf(yv);
                    }
                }
                *(bf8_t*)(raw + ((i * 256 + c16 * 16) ^ ((i & 7) << 4))) = v8;
            }
        }
    } else {
        const unsigned short* src = nf + (size_t)b * D_ * G_;
        #pragma unroll
        for (int p = 0; p < 2; ++p) {
            int task = tid + p * 512;
            if (task < HALO_ROWS * 16) {
                int i = task >> 4, c16 = task & 15;
                int t = t0 - 15 + i;
                bf8_t v = {0, 0, 0, 0, 0, 0, 0, 0};
                if (t >= 0 && t < D_) v = *(const bf8_t*)(src + (size_t)t * G_ + c16 * 8);
                *(bf8_t*)(raw + ((i * 256 + c16 * 16) ^ ((i & 7) << 4))) = v;
            }
        }
    }
    __syncthreads();

    // aggregate: 1024 tasks over 512 threads (2 each), computed ONCE
    #pragma unroll
    for (int p = 0; p < 2; ++p) {
        int task = tid + p * 512;
        int c16 = task & 15, rel = (task >> 4) & 3, row = task >> 6;   // row 0..15
        int t = t0 + row;
        int ctr = row + 15;
        float s[8] = {0.f,0.f,0.f,0.f,0.f,0.f,0.f,0.f};
        float scale = 1.f;
        if (rel == 0) {
            bf8_t v = *(const bf8_t*)(raw + ((ctr * 256 + c16 * 16) ^ ((ctr & 7) << 4)));
            #pragma unroll
            for (int e = 0; e < 8; ++e) s[e] = bf2f((unsigned short)v[e]);
        } else if (rel == 1) {
            #pragma unroll
            for (int o = 1; o <= 5; ++o) if (t + o < D_) {
                int i = ctr + o;
                bf8_t v = *(const bf8_t*)(raw + ((i * 256 + c16 * 16) ^ ((i & 7) << 4)));
                #pragma unroll
                for (int e = 0; e < 8; ++e) s[e] += bf2f((unsigned short)v[e]);
            }
            scale = 1.f / (float)max(min(5, D_ - 1 - t), 1);
        } else if (rel == 2) {
            #pragma unroll
            for (int o = 1; o <= 5; ++o) if (t - o >= 0) {
                int i = ctr - o;
                bf8_t v = *(const bf8_t*)(raw + ((i * 256 + c16 * 16) ^ ((i & 7) << 4)));
                #pragma unroll
                for (int e = 0; e < 8; ++e) s[e] += bf2f((unsigned short)v[e]);
            }
            scale = 1.f / (float)max(min(5, t), 1);
        } else {
            int cnt = 0;
            if (t >= 15) {
                int i = ctr - 15;
                bf8_t v = *(const bf8_t*)(raw + ((i * 256 + c16 * 16) ^ ((i & 7) << 4)));
                #pragma unroll
                for (int e = 0; e < 8; ++e) s[e] += bf2f((unsigned short)v[e]);
                cnt++;
            }
            if (t + 15 < D_) {
                int i = ctr + 15;
                bf8_t v = *(const bf8_t*)(raw + ((i * 256 + c16 * 16) ^ ((i & 7) << 4)));
                #pragma unroll
                for (int e = 0; e < 8; ++e) s[e] += bf2f((unsigned short)v[e]);
                cnt++;
            }
            scale = 1.f / (float)max(cnt, 1);
        }
        bf8_t o8;
        #pragma unroll
        for (int e = 0; e < 8; ++e) o8[e] = (short)f2bf(s[e] * scale);
        *(bf8_t*)(agg + ((row * 1024 + rel * 256 + c16 * 16) ^ ((row & 7) << 4))) = o8;
    }
    __syncthreads();

    // K=512 MFMA: wave wv (0..7) -> col16 = wv  (covers all 128 cols once)
    int l = tid & 63, wv = tid >> 6;
    int l15 = l & 15, kgrp = l >> 4;
    int col16 = wv;
    f32x4_t acc = (f32x4_t){0.f, 0.f, 0.f, 0.f};

    for (int ks = 0; ks < 16; ++ks) {
        int rel = ks >> 2, kk = ks & 3;
        bf8_t a = *(const bf8_t*)(agg +
            ((l15 * 1024 + rel * 256 + kk * 64 + kgrp * 16) ^ ((l15 & 7) << 4)));
        bf8_t bf = *(const bf8_t*)(wt + rel * 16384 +
            (size_t)(col16 * 16 + l15) * G_ + kk * 32 + kgrp * 8);
        acc = __builtin_amdgcn_mfma_f32_16x16x32_bf16(a, bf, acc, 0, 0, 0);
    }

    unsigned short* outb = out + (size_t)b * D_ * G_;
    int rbase = t0 + kgrp * 4;
    int col = col16 * 16 + l15;
    float rbv = rb[col];
    #pragma unroll
    for (int j = 0; j < 4; ++j)
        outb[(size_t)(rbase + j) * G_ + col] = f2bf(acc[j] + rbv);
}

// ------ fused QKVS + attention + BN partials, 512-thread merged-y -------
__global__ __launch_bounds__(512, 4) void qkvs_attn_kernel(
    const unsigned short* __restrict__ nf1,
    const unsigned short* __restrict__ wt,  // 4 mats: q,k,v,skip
    const float* __restrict__ bq, const float* __restrict__ bk,
    const float* __restrict__ bv, const float* __restrict__ bsk,
    float* __restrict__ out2, float* __restrict__ partials)
{
    __shared__ char raw[HALO_ROWS * 256];             // 12 KB (swizzled halo)
    __shared__ unsigned short kls[HALO_ROWS * 128];   // 12 KB (full 128 cols)
    __shared__ unsigned short vls[HALO_ROWS * 128];   // 12 KB
    __shared__ unsigned short qls[R_ * 128];          // 4 KB
    __shared__ float sls[R_ * 128];                   // 8 KB
    int blk = xcd_swz(blockIdx.x);
    int tid = threadIdx.x;           // 0..511
    int b = blk >> 7, t0 = (blk & 127) * R_;

    {   // stage halo ONCE
        const unsigned short* src = nf1 + (size_t)b * D_ * G_;
        #pragma unroll
        for (int p = 0; p < 2; ++p) {
            int task = tid + p * 512;
            if (task < HALO_ROWS * 16) {
                int i = task >> 4, c16 = task & 15;
                int t = t0 - 15 + i;
                bf8_t v = {0, 0, 0, 0, 0, 0, 0, 0};
                if (t >= 0 && t < D_) v = *(const bf8_t*)(src + (size_t)t * G_ + c16 * 8);
                *(bf8_t*)(raw + ((i * 256 + c16 * 16) ^ ((i & 7) << 4))) = v;
            }
        }
    }
    __syncthreads();

    int l = tid & 63, wvid = tid >> 6;      // wvid 0..7
    int l15 = l & 15, kgrp = l >> 4;
    // 16 jobs: job = wvid + i*8; y = job>>3, jj = job&7
    #pragma unroll
    for (int i = 0; i < 2; ++i) {
        int job = wvid + i * 8;
        int y = job >> 3, jj = job & 7;
        int m, frag;
        if (jj < 3)      { m = 1; frag = jj; }        // K
        else if (jj < 6) { m = 2; frag = jj - 3; }    // V
        else if (jj == 6){ m = 0; frag = 0; }         // Q
        else             { m = 3; frag = 0; }         // S
        bool halo = (m == 1) | (m == 2);
        int rawrow = halo ? (frag * 16 + l15) : (15 + l15);
        const unsigned short* wm = wt + (size_t)m * 16384;
        const float* bias = (m == 0) ? bq : (m == 1) ? bk : (m == 2) ? bv : bsk;

        bf8_t a[4];
        #pragma unroll
        for (int kc = 0; kc < 4; ++kc)
            a[kc] = *(const bf8_t*)(raw +
                ((rawrow * 256 + kc * 64 + kgrp * 16) ^ ((rawrow & 7) << 4)));
        f32x4_t acc[4];
        #pragma unroll
        for (int n = 0; n < 4; ++n) acc[n] = (f32x4_t){0.f, 0.f, 0.f, 0.f};
        #pragma unroll
        for (int kc = 0; kc < 4; ++kc) {
            #pragma unroll
            for (int n = 0; n < 4; ++n) {
                int col = y * 64 + n * 16 + l15;
                bf8_t bf = *(const bf8_t*)(wm +
                    (size_t)col * G_ + kc * 32 + kgrp * 8);
                acc[n] = __builtin_amdgcn_mfma_f32_16x16x32_bf16(a[kc], bf, acc[n], 0, 0, 0);
            }
        }
        int r0 = frag * 16 + kgrp * 4;
        #pragma unroll
        for (int n = 0; n < 4; ++n) {
            int gc = y * 64 + n * 16 + l15;     // global col 0..127
            float bb = bias[gc];
            #pragma unroll
            for (int j = 0; j < 4; ++j) {
                float v = acc[n][j] + bb;
                int rr = r0 + j;
                if (m == 1)      kls[rr * 128 + gc] = f2bf(v);
                else if (m == 2) vls[rr * 128 + gc] = f2bf(v);
                else if (m == 0) qls[rr * 128 + gc] = f2bf(v);
                else             sls[rr * 128 + gc] = v;
            }
        }
    }
    __syncthreads();

    // attention: j = tid&127 (all cols), grp = tid>>7 (0..3); 4 iters x 4 rows
    int j = tid & 127, grp = tid >> 7;
    const float invs = 0.17677669529663687f;  // 1/sqrt(32)
    float ps = 0.f, pss = 0.f;
    float* o2b = out2 + (size_t)b * D_ * G_;
    const int offs[13] = {0, 1, 2, 3, 4, 5, -1, -2, -3, -4, -5, -15, 15};
    for (int it = 0; it < 4; ++it) {
        int tl = it * 4 + grp;             // 0..15
        int t = t0 + tl;
        float q = bf2f(qls[tl * 128 + j]);
        float lg[13], vv[13];
        #pragma unroll
        for (int n = 0; n < 13; ++n) {
            int ts = t + offs[n];
            bool ok = (ts >= 0) && (ts < D_);
            int ki = tl + 15 + offs[n];    // 0..45
            float kk = ok ? bf2f(kls[ki * 128 + j]) : 0.f;
            vv[n] = ok ? bf2f(vls[ki * 128 + j]) : 0.f;
            float p = q * kk;
            p += __shfl_xor(p, 16, 32);
            p += __shfl_xor(p, 8, 32);
            p += __shfl_xor(p, 4, 32);
            p += __shfl_xor(p, 2, 32);
            p += __shfl_xor(p, 1, 32);
            lg[n] = ok ? p * invs : -1e30f;
        }
        float m = lg[0];
        #pragma unroll
        for (int n = 1; n < 13; ++n) m = fmaxf(m, lg[n]);
        float den = 0.f, aggv = 0.f;
        #pragma unroll
        for (int n = 0; n < 13; ++n) {
            float e = expf(lg[n] - m);
            den += e;
            aggv += e * vv[n];
        }
        float o = aggv / den + sls[tl * 128 + j];
        o2b[(size_t)t * G_ + j] = o;
        ps += o; pss += o * o;
    }

    __syncthreads();
    float* red = (float*)raw;               // 4 KB of the 12 KB raw buffer
    red[grp * 128 + j] = ps;
    red[512 + grp * 128 + j] = pss;
    __syncthreads();
    if (tid < 128) {
        float s = 0.f, ss = 0.f;
        #pragma unroll
        for (int g = 0; g < 4; ++g) {
            s += red[g * 128 + tid];
            ss += red[512 + g * 128 + tid];
        }
        float* P = partials + ((size_t)b * 128 + (blk & 127)) * 256;
        P[tid] = s;
        P[128 + tid] = ss;
    }
}

// ------ BatchNorm apply (final -> d_out): 512 blocks x 16 rows ----------
// PROVEN r17 — unchanged.
__global__ __launch_bounds__(256) void bn_apply_kernel(
    const float* __restrict__ X, const float* __restrict__ partials,
    const float* __restrict__ gam, const float* __restrict__ bet,
    float* __restrict__ out)
{
    int blk = blockIdx.x;       // 0..511
    int b = blk >> 7;           // 0..3
    int chunk = blk & 127;      // 16-row slice
    int tid = threadIdx.x;
    __shared__ float smu[G_], sinv[G_];
    __shared__ float sred[2][G_], ssred[2][G_];
    {
        int halfk = tid >> 7;
        int c = tid & 127;
        float s = 0.f, ss = 0.f;
        const float* P = partials + (size_t)b * 128 * 256;
        #pragma unroll 4
        for (int k = halfk * 64; k < halfk * 64 + 64; ++k) {
            s += P[k * 256 + c];
            ss += P[k * 256 + G_ + c];
        }
        sred[halfk][c] = s;
        ssred[halfk][c] = ss;
    }
    __syncthreads();
    if (tid < G_) {
        float S = sred[0][tid] + sred[1][tid];
        float SS = ssred[0][tid] + ssred[1][tid];
        float mu = S / D_;
        float var = SS / D_ - mu * mu;
        smu[tid] = mu;
        sinv[tid] = 1.0f / sqrtf(var + 1e-5f);
    }
    __syncthreads();

    const float4* base4 = (const float4*)(X + ((size_t)b * D_ + chunk * 16) * G_);
    float4* ob4 = (float4*)(out + ((size_t)b * D_ + chunk * 16) * G_);
    int c4 = (tid & 31) * 4;
    float m0 = smu[c4], m1 = smu[c4 + 1], m2 = smu[c4 + 2], m3 = smu[c4 + 3];
    float i0 = sinv[c4] * gam[c4],     i1 = sinv[c4 + 1] * gam[c4 + 1];
    float i2 = sinv[c4 + 2] * gam[c4 + 2], i3 = sinv[c4 + 3] * gam[c4 + 3];
    float b0 = bet[c4], b1 = bet[c4 + 1], b2 = bet[c4 + 2], b3 = bet[c4 + 3];
    #pragma unroll
    for (int p = 0; p < 2; ++p) {
        float4 v = base4[p * 256 + tid];
        float4 y;
        y.x = (v.x - m0) * i0 + b0;
        y.y = (v.y - m1) * i1 + b1;
        y.z = (v.z - m2) * i2 + b2;
        y.w = (v.w - m3) * i3 + b3;
        y.x = (y.x > 0.f) ? y.x : 0.01f * y.x;
        y.y = (y.y > 0.f) ? y.y : 0.01f * y.y;
        y.z = (y.z > 0.f) ? y.z : 0.01f * y.z;
        y.w = (y.w > 0.f) ? y.w : 0.01f * y.w;
        ob4[p * 256 + tid] = y;
    }
}

extern "C" void kernel_launch(void* const* d_in, const int* in_sizes, int n_in,
                              void* d_out, int out_size, void* d_ws, size_t ws_size,
                              hipStream_t stream)
{
    (void)in_sizes; (void)n_in; (void)out_size; (void)ws_size;
    const float* x      = (const float*)d_in[0];
    const float* fe_w   = (const float*)d_in[3];
    const float* fe_b   = (const float*)d_in[4];
    const float* ln_g   = (const float*)d_in[5];
    const float* ln_b   = (const float*)d_in[6];
    const float* w_rel  = (const float*)d_in[7];   // [2][4][128][128]
    const float* w_root = (const float*)d_in[8];   // [2][128][128]
    const float* rgcn_b = (const float*)d_in[9];   // [2][128]
    const float* wq  = (const float*)d_in[10];
    const float* bq  = (const float*)d_in[11];
    const float* wk  = (const float*)d_in[12];
    const float* bk  = (const float*)d_in[13];
    const float* wv  = (const float*)d_in[14];
    const float* bv  = (const float*)d_in[15];
    const float* wsk = (const float*)d_in[16];
    const float* bsk = (const float*)d_in[17];
    const float* bn_g = (const float*)d_in[18];
    const float* bn_b = (const float*)d_in[19];

    float* ws   = (float*)d_ws;
    float* out2 = ws;                                  // [8192][128] f32
    float* partials = out2 + (size_t)NODES * G_;       // [4][128][256] f32
    unsigned short* nf_bf  = (unsigned short*)(partials + 4 * 128 * 256);
    unsigned short* nf1_bf = nf_bf + (size_t)NODES * G_;
    unsigned short* wbf    = nf1_bf + (size_t)NODES * G_;   // 16 x [128][128]

    WconvArgs wa;
    for (int l = 0; l < 2; ++l) {
        for (int r = 0; r < 4; ++r) {
            wa.src[l * 8 + r] = w_rel + ((size_t)l * 4 + r) * G_ * G_;
            wa.add[l * 8 + r] = (r == 0) ? (w_root + (size_t)l * G_ * G_) : nullptr;
        }
        wa.src[l * 8 + 4] = wq  + (size_t)l * G_ * G_; wa.add[l * 8 + 4] = nullptr;
        wa.src[l * 8 + 5] = wk  + (size_t)l * G_ * G_; wa.add[l * 8 + 5] = nullptr;
        wa.src[l * 8 + 6] = wv  + (size_t)l * G_ * G_; wa.add[l * 8 + 6] = nullptr;
        wa.src[l * 8 + 7] = wsk + (size_t)l * G_ * G_; wa.add[l * 8 + 7] = nullptr;
    }

    pool_fc_ln_kernel<<<NODES, 192, 0, stream>>>(
        x, fe_w, fe_b, ln_g, ln_b, nf_bf, wa, wbf);

    // ---- layer 0 ----
    rgcn_fused_kernel<false><<<512, 512, 0, stream>>>(
        nf_bf, nullptr, nullptr, nullptr, nullptr,
        wbf, rgcn_b, nf1_bf);
    qkvs_attn_kernel<<<512, 512, 0, stream>>>(
        nf1_bf, wbf + (size_t)4 * 16384,
        bq, bk, bv, bsk, out2, partials);

    // ---- layer 1 (BN of layer-0 folded into rgcn staging) ----
    rgcn_fused_kernel<true><<<512, 512, 0, stream>>>(
        nullptr, out2, partials, bn_g, bn_b,
        wbf + (size_t)8 * 16384, rgcn_b + G_, nf1_bf);
    qkvs_attn_kernel<<<512, 512, 0, stream>>>(
        nf1_bf, wbf + (size_t)12 * 16384,
        bq + G_, bk + G_, bv + G_, bsk + G_, out2, partials);

    bn_apply_kernel<<<512, 256, 0, stream>>>(
        out2, partials, bn_g + G_, bn_b + G_, (float*)d_out);
}

// Round 19
// 206.299 us; speedup vs baseline: 3.0397x; 1.0065x over previous
//
#include <hip/hip_runtime.h>
#include <hip/hip_bf16.h>

#define B_ 4
#define D_ 2048
#define HWS 64
#define C_ 192
#define G_ 128
#define NODES (B_*D_)   // 8192
#define R_ 16           // central rows per fused block
#define HALO_ROWS 48    // t0-15 .. t0+32 staged

typedef short bf8_t  __attribute__((ext_vector_type(8)));   // 8 bf16 (4 VGPR)
typedef float f32x4_t __attribute__((ext_vector_type(4)));

__device__ inline unsigned short f2bf(float f) {
    unsigned int u = __builtin_bit_cast(unsigned int, f);
    unsigned int r = (u + 0x7fffu + ((u >> 16) & 1u)) >> 16;   // RNE
    return (unsigned short)r;
}
__device__ inline float bf2f(unsigned short h) {
    unsigned int u = ((unsigned int)h) << 16;
    return __builtin_bit_cast(float, u);
}

// XCD-aware bijective swizzle for 512-block x-dim (8 XCDs, 512%8==0).
__device__ inline int xcd_swz(int x) { return (x & 7) * 64 + (x >> 3); }

struct WconvArgs {
    const float* src[16];
    const float* add[16];   // null or w_root slice (folded into slot 0)
};

// ---------------- K1: pool + FC + LayerNorm  (+ folded weight conv) -----
// PROVEN r16-r18 — unchanged.
__global__ __launch_bounds__(192) void pool_fc_ln_kernel(
    const float* __restrict__ x, const float* __restrict__ W,
    const float* __restrict__ bias, const float* __restrict__ gam,
    const float* __restrict__ bet, unsigned short* __restrict__ nf,
    WconvArgs wa, unsigned short* __restrict__ wbf)
{
    int u = blockIdx.x;            // 0..8191 (= b*2048 + t)
    int tid = threadIdx.x;         // 0..191
    __shared__ float feat[C_];
    __shared__ float4 red4[4][48];
    __shared__ float red[4];
    __shared__ float stats[2];

    const float4* xb4 = (const float4*)(x + (size_t)u * (HWS * C_)); // 48 f4/row
    int cg = tid % 48;
    int rg = tid / 48;             // 0..3
    float4 a = make_float4(0.f, 0.f, 0.f, 0.f);
    #pragma unroll
    for (int s = 0; s < HWS; s += 4) {
        float4 v = xb4[(size_t)(s + rg) * 48 + cg];
        a.x += v.x; a.y += v.y; a.z += v.z; a.w += v.w;
    }
    red4[rg][cg] = a;
    __syncthreads();
    if (rg == 0) {
        float4 b0 = red4[0][cg], b1 = red4[1][cg], b2 = red4[2][cg], b3 = red4[3][cg];
        feat[cg * 4 + 0] = (b0.x + b1.x + b2.x + b3.x) * (1.0f / HWS);
        feat[cg * 4 + 1] = (b0.y + b1.y + b2.y + b3.y) * (1.0f / HWS);
        feat[cg * 4 + 2] = (b0.z + b1.z + b2.z + b3.z) * (1.0f / HWS);
        feat[cg * 4 + 3] = (b0.w + b1.w + b2.w + b3.w) * (1.0f / HWS);
    }
    __syncthreads();

    float h = 0.f;
    if (tid < G_) {
        h = bias[tid];
        #pragma unroll 4
        for (int c = 0; c < C_; ++c) h += feat[c] * W[c * G_ + tid];
    }
    float s1 = (tid < G_) ? h : 0.f;
    float s2 = (tid < G_) ? h * h : 0.f;
    #pragma unroll
    for (int off = 32; off >= 1; off >>= 1) {
        s1 += __shfl_xor(s1, off, 64);
        s2 += __shfl_xor(s2, off, 64);
    }
    int wid = tid >> 6;
    if ((tid & 63) == 0 && wid < 2) { red[wid] = s1; red[2 + wid] = s2; }
    __syncthreads();
    if (tid == 0) {
        float S = red[0] + red[1];
        float SS = red[2] + red[3];
        float mu = S / G_;
        float var = SS / G_ - mu * mu;
        stats[0] = mu;
        stats[1] = 1.0f / sqrtf(var + 1e-5f);
    }
    __syncthreads();
    if (tid < G_) {
        float v = (h - stats[0]) * stats[1] * gam[tid] + bet[tid];
        nf[(size_t)u * G_ + tid] = f2bf(v);
    }

    if (u < 2048 && tid < 128) {
        int idx = u * 128 + tid;           // 0..262143
        int m = idx >> 14;                 // 0..15
        int within = idx & 16383;          // n*128 + k
        int n = within >> 7, k = within & 127;
        float v = wa.src[m][k * G_ + n];
        if (wa.add[m]) v += wa.add[m][k * G_ + n];
        wbf[(size_t)m * 16384 + within] = f2bf(v);
    }
}

// ------ fused RGCN, 512-thread merged-y (r18 body); xin now bf16 --------
template <bool BNIN>
__global__ __launch_bounds__(512, 4) void rgcn_fused_kernel(
    const unsigned short* __restrict__ nf, const unsigned short* __restrict__ xin,
    const float* __restrict__ partials, const float* __restrict__ gam,
    const float* __restrict__ bet,
    const unsigned short* __restrict__ wt,   // 4 mats [128 n][128 k] bf16
    const float* __restrict__ rb,
    unsigned short* __restrict__ out)
{
    __shared__ char raw[HALO_ROWS * 256];   // 12 KB halo (swizzled)
    __shared__ char agg[R_ * 1024];         // 16 KB
    __shared__ float smu[G_], sivg[G_], sbet[G_];
    __shared__ float sred[2][G_], ssred[2][G_];
    int blk = xcd_swz(blockIdx.x);
    int b = blk >> 7;
    int t0 = (blk & 127) * R_;
    int tid = threadIdx.x;          // 0..511

    if constexpr (BNIN) {
        if (tid < 256) {
            int halfk = tid >> 7;
            int c = tid & 127;
            float s = 0.f, ss = 0.f;
            const float* P = partials + (size_t)b * 128 * 256;
            #pragma unroll 4
            for (int k = halfk * 64; k < halfk * 64 + 64; ++k) {
                s += P[k * 256 + c];
                ss += P[k * 256 + G_ + c];
            }
            sred[halfk][c] = s;
            ssred[halfk][c] = ss;
        }
        __syncthreads();
        if (tid < G_) {
            float S = sred[0][tid] + sred[1][tid];
            float SS = ssred[0][tid] + ssred[1][tid];
            float mu = S / D_;
            float var = SS / D_ - mu * mu;
            float inv = 1.0f / sqrtf(var + 1e-5f);
            smu[tid] = mu;
            sivg[tid] = inv * gam[tid];
            sbet[tid] = bet[tid];
        }
        __syncthreads();
        const unsigned short* xb = xin + (size_t)b * D_ * G_;
        #pragma unroll
        for (int p = 0; p < 2; ++p) {
            int task = tid + p * 512;
            if (task < HALO_ROWS * 16) {
                int i = task >> 4, c16 = task & 15;
                int t = t0 - 15 + i;
                bf8_t v8 = {0, 0, 0, 0, 0, 0, 0, 0};
                if (t >= 0 && t < D_) {
                    bf8_t vin = *(const bf8_t*)(xb + (size_t)t * G_ + c16 * 8);
                    #pragma unroll
                    for (int e = 0; e < 8; ++e) {
                        int c = c16 * 8 + e;
                        float yv = (bf2f((unsigned short)vin[e]) - smu[c]) * sivg[c] + sbet[c];
                        yv = (yv > 0.f) ? yv : 0.01f * yv;
                        v8[e] = (short)f2bf(yv);
                    }
                }
                *(bf8_t*)(raw + ((i * 256 + c16 * 16) ^ ((i & 7) << 4))) = v8;
            }
        }
    } else {
        const unsigned short* src = nf + (size_t)b * D_ * G_;
        #pragma unroll
        for (int p = 0; p < 2; ++p) {
            int task = tid + p * 512;
            if (task < HALO_ROWS * 16) {
                int i = task >> 4, c16 = task & 15;
                int t = t0 - 15 + i;
                bf8_t v = {0, 0, 0, 0, 0, 0, 0, 0};
                if (t >= 0 && t < D_) v = *(const bf8_t*)(src + (size_t)t * G_ + c16 * 8);
                *(bf8_t*)(raw + ((i * 256 + c16 * 16) ^ ((i & 7) << 4))) = v;
            }
        }
    }
    __syncthreads();

    // aggregate: 1024 tasks over 512 threads (2 each), computed ONCE
    #pragma unroll
    for (int p = 0; p < 2; ++p) {
        int task = tid + p * 512;
        int c16 = task & 15, rel = (task >> 4) & 3, row = task >> 6;   // row 0..15
        int t = t0 + row;
        int ctr = row + 15;
        float s[8] = {0.f,0.f,0.f,0.f,0.f,0.f,0.f,0.f};
        float scale = 1.f;
        if (rel == 0) {
            bf8_t v = *(const bf8_t*)(raw + ((ctr * 256 + c16 * 16) ^ ((ctr & 7) << 4)));
            #pragma unroll
            for (int e = 0; e < 8; ++e) s[e] = bf2f((unsigned short)v[e]);
        } else if (rel == 1) {
            #pragma unroll
            for (int o = 1; o <= 5; ++o) if (t + o < D_) {
                int i = ctr + o;
                bf8_t v = *(const bf8_t*)(raw + ((i * 256 + c16 * 16) ^ ((i & 7) << 4)));
                #pragma unroll
                for (int e = 0; e < 8; ++e) s[e] += bf2f((unsigned short)v[e]);
            }
            scale = 1.f / (float)max(min(5, D_ - 1 - t), 1);
        } else if (rel == 2) {
            #pragma unroll
            for (int o = 1; o <= 5; ++o) if (t - o >= 0) {
                int i = ctr - o;
                bf8_t v = *(const bf8_t*)(raw + ((i * 256 + c16 * 16) ^ ((i & 7) << 4)));
                #pragma unroll
                for (int e = 0; e < 8; ++e) s[e] += bf2f((unsigned short)v[e]);
            }
            scale = 1.f / (float)max(min(5, t), 1);
        } else {
            int cnt = 0;
            if (t >= 15) {
                int i = ctr - 15;
                bf8_t v = *(const bf8_t*)(raw + ((i * 256 + c16 * 16) ^ ((i & 7) << 4)));
                #pragma unroll
                for (int e = 0; e < 8; ++e) s[e] += bf2f((unsigned short)v[e]);
                cnt++;
            }
            if (t + 15 < D_) {
                int i = ctr + 15;
                bf8_t v = *(const bf8_t*)(raw + ((i * 256 + c16 * 16) ^ ((i & 7) << 4)));
                #pragma unroll
                for (int e = 0; e < 8; ++e) s[e] += bf2f((unsigned short)v[e]);
                cnt++;
            }
            scale = 1.f / (float)max(cnt, 1);
        }
        bf8_t o8;
        #pragma unroll
        for (int e = 0; e < 8; ++e) o8[e] = (short)f2bf(s[e] * scale);
        *(bf8_t*)(agg + ((row * 1024 + rel * 256 + c16 * 16) ^ ((row & 7) << 4))) = o8;
    }
    __syncthreads();

    // K=512 MFMA: wave wv (0..7) -> col16 = wv
    int l = tid & 63, wv = tid >> 6;
    int l15 = l & 15, kgrp = l >> 4;
    int col16 = wv;
    f32x4_t acc = (f32x4_t){0.f, 0.f, 0.f, 0.f};

    for (int ks = 0; ks < 16; ++ks) {
        int rel = ks >> 2, kk = ks & 3;
        bf8_t a = *(const bf8_t*)(agg +
            ((l15 * 1024 + rel * 256 + kk * 64 + kgrp * 16) ^ ((l15 & 7) << 4)));
        bf8_t bf = *(const bf8_t*)(wt + rel * 16384 +
            (size_t)(col16 * 16 + l15) * G_ + kk * 32 + kgrp * 8);
        acc = __builtin_amdgcn_mfma_f32_16x16x32_bf16(a, bf, acc, 0, 0, 0);
    }

    unsigned short* outb = out + (size_t)b * D_ * G_;
    int rbase = t0 + kgrp * 4;
    int col = col16 * 16 + l15;
    float rbv = rb[col];
    #pragma unroll
    for (int j = 0; j < 4; ++j)
        outb[(size_t)(rbase + j) * G_ + col] = f2bf(acc[j] + rbv);
}

// ------ fused QKVS + attention + BN partials (r18 body); out2 bf16 ------
__global__ __launch_bounds__(512, 4) void qkvs_attn_kernel(
    const unsigned short* __restrict__ nf1,
    const unsigned short* __restrict__ wt,  // 4 mats: q,k,v,skip
    const float* __restrict__ bq, const float* __restrict__ bk,
    const float* __restrict__ bv, const float* __restrict__ bsk,
    unsigned short* __restrict__ out2, float* __restrict__ partials)
{
    __shared__ char raw[HALO_ROWS * 256];             // 12 KB (swizzled halo)
    __shared__ unsigned short kls[HALO_ROWS * 128];   // 12 KB
    __shared__ unsigned short vls[HALO_ROWS * 128];   // 12 KB
    __shared__ unsigned short qls[R_ * 128];          // 4 KB
    __shared__ float sls[R_ * 128];                   // 8 KB
    int blk = xcd_swz(blockIdx.x);
    int tid = threadIdx.x;           // 0..511
    int b = blk >> 7, t0 = (blk & 127) * R_;

    {   // stage halo ONCE
        const unsigned short* src = nf1 + (size_t)b * D_ * G_;
        #pragma unroll
        for (int p = 0; p < 2; ++p) {
            int task = tid + p * 512;
            if (task < HALO_ROWS * 16) {
                int i = task >> 4, c16 = task & 15;
                int t = t0 - 15 + i;
                bf8_t v = {0, 0, 0, 0, 0, 0, 0, 0};
                if (t >= 0 && t < D_) v = *(const bf8_t*)(src + (size_t)t * G_ + c16 * 8);
                *(bf8_t*)(raw + ((i * 256 + c16 * 16) ^ ((i & 7) << 4))) = v;
            }
        }
    }
    __syncthreads();

    int l = tid & 63, wvid = tid >> 6;      // wvid 0..7
    int l15 = l & 15, kgrp = l >> 4;
    #pragma unroll
    for (int i = 0; i < 2; ++i) {
        int job = wvid + i * 8;
        int y = job >> 3, jj = job & 7;
        int m, frag;
        if (jj < 3)      { m = 1; frag = jj; }        // K
        else if (jj < 6) { m = 2; frag = jj - 3; }    // V
        else if (jj == 6){ m = 0; frag = 0; }         // Q
        else             { m = 3; frag = 0; }         // S
        bool halo = (m == 1) | (m == 2);
        int rawrow = halo ? (frag * 16 + l15) : (15 + l15);
        const unsigned short* wm = wt + (size_t)m * 16384;
        const float* bias = (m == 0) ? bq : (m == 1) ? bk : (m == 2) ? bv : bsk;

        bf8_t a[4];
        #pragma unroll
        for (int kc = 0; kc < 4; ++kc)
            a[kc] = *(const bf8_t*)(raw +
                ((rawrow * 256 + kc * 64 + kgrp * 16) ^ ((rawrow & 7) << 4)));
        f32x4_t acc[4];
        #pragma unroll
        for (int n = 0; n < 4; ++n) acc[n] = (f32x4_t){0.f, 0.f, 0.f, 0.f};
        #pragma unroll
        for (int kc = 0; kc < 4; ++kc) {
            #pragma unroll
            for (int n = 0; n < 4; ++n) {
                int col = y * 64 + n * 16 + l15;
                bf8_t bf = *(const bf8_t*)(wm +
                    (size_t)col * G_ + kc * 32 + kgrp * 8);
                acc[n] = __builtin_amdgcn_mfma_f32_16x16x32_bf16(a[kc], bf, acc[n], 0, 0, 0);
            }
        }
        int r0 = frag * 16 + kgrp * 4;
        #pragma unroll
        for (int n = 0; n < 4; ++n) {
            int gc = y * 64 + n * 16 + l15;     // global col 0..127
            float bb = bias[gc];
            #pragma unroll
            for (int j = 0; j < 4; ++j) {
                float v = acc[n][j] + bb;
                int rr = r0 + j;
                if (m == 1)      kls[rr * 128 + gc] = f2bf(v);
                else if (m == 2) vls[rr * 128 + gc] = f2bf(v);
                else if (m == 0) qls[rr * 128 + gc] = f2bf(v);
                else             sls[rr * 128 + gc] = v;
            }
        }
    }
    __syncthreads();

    int j = tid & 127, grp = tid >> 7;
    const float invs = 0.17677669529663687f;  // 1/sqrt(32)
    float ps = 0.f, pss = 0.f;
    unsigned short* o2b = out2 + (size_t)b * D_ * G_;
    const int offs[13] = {0, 1, 2, 3, 4, 5, -1, -2, -3, -4, -5, -15, 15};
    for (int it = 0; it < 4; ++it) {
        int tl = it * 4 + grp;             // 0..15
        int t = t0 + tl;
        float q = bf2f(qls[tl * 128 + j]);
        float lg[13], vv[13];
        #pragma unroll
        for (int n = 0; n < 13; ++n) {
            int ts = t + offs[n];
            bool ok = (ts >= 0) && (ts < D_);
            int ki = tl + 15 + offs[n];    // 0..45
            float kk = ok ? bf2f(kls[ki * 128 + j]) : 0.f;
            vv[n] = ok ? bf2f(vls[ki * 128 + j]) : 0.f;
            float p = q * kk;
            p += __shfl_xor(p, 16, 32);
            p += __shfl_xor(p, 8, 32);
            p += __shfl_xor(p, 4, 32);
            p += __shfl_xor(p, 2, 32);
            p += __shfl_xor(p, 1, 32);
            lg[n] = ok ? p * invs : -1e30f;
        }
        float m = lg[0];
        #pragma unroll
        for (int n = 1; n < 13; ++n) m = fmaxf(m, lg[n]);
        float den = 0.f, aggv = 0.f;
        #pragma unroll
        for (int n = 0; n < 13; ++n) {
            float e = expf(lg[n] - m);
            den += e;
            aggv += e * vv[n];
        }
        float o = aggv / den + sls[tl * 128 + j];
        o2b[(size_t)t * G_ + j] = f2bf(o);
        ps += o; pss += o * o;
    }

    __syncthreads();
    float* red = (float*)raw;
    red[grp * 128 + j] = ps;
    red[512 + grp * 128 + j] = pss;
    __syncthreads();
    if (tid < 128) {
        float s = 0.f, ss = 0.f;
        #pragma unroll
        for (int g = 0; g < 4; ++g) {
            s += red[g * 128 + tid];
            ss += red[512 + g * 128 + tid];
        }
        float* P = partials + ((size_t)b * 128 + (blk & 127)) * 256;
        P[tid] = s;
        P[128 + tid] = ss;
    }
}

// ------ BatchNorm apply (final -> d_out f32): X now bf16 ----------------
__global__ __launch_bounds__(256) void bn_apply_kernel(
    const unsigned short* __restrict__ X, const float* __restrict__ partials,
    const float* __restrict__ gam, const float* __restrict__ bet,
    float* __restrict__ out)
{
    int blk = blockIdx.x;       // 0..511
    int b = blk >> 7;           // 0..3
    int chunk = blk & 127;      // 16-row slice
    int tid = threadIdx.x;
    __shared__ float smu[G_], sivg[G_], sbet[G_];
    __shared__ float sred[2][G_], ssred[2][G_];
    {
        int halfk = tid >> 7;
        int c = tid & 127;
        float s = 0.f, ss = 0.f;
        const float* P = partials + (size_t)b * 128 * 256;
        #pragma unroll 4
        for (int k = halfk * 64; k < halfk * 64 + 64; ++k) {
            s += P[k * 256 + c];
            ss += P[k * 256 + G_ + c];
        }
        sred[halfk][c] = s;
        ssred[halfk][c] = ss;
    }
    __syncthreads();
    if (tid < G_) {
        float S = sred[0][tid] + sred[1][tid];
        float SS = ssred[0][tid] + ssred[1][tid];
        float mu = S / D_;
        float var = SS / D_ - mu * mu;
        float inv = 1.0f / sqrtf(var + 1e-5f);
        smu[tid] = mu;
        sivg[tid] = inv * gam[tid];
        sbet[tid] = bet[tid];
    }
    __syncthreads();

    // thread -> (row = tid>>4, 8 cols at c8 = (tid&15)*8); 16x128 slab
    int row = tid >> 4;
    int c8 = (tid & 15) * 8;
    size_t base = ((size_t)b * D_ + chunk * 16 + row) * G_ + c8;
    bf8_t v8 = *(const bf8_t*)(X + base);
    float4 y0, y1;
    float yv[8];
    #pragma unroll
    for (int e = 0; e < 8; ++e) {
        int c = c8 + e;
        float y = (bf2f((unsigned short)v8[e]) - smu[c]) * sivg[c] + sbet[c];
        yv[e] = (y > 0.f) ? y : 0.01f * y;
    }
    y0.x = yv[0]; y0.y = yv[1]; y0.z = yv[2]; y0.w = yv[3];
    y1.x = yv[4]; y1.y = yv[5]; y1.z = yv[6]; y1.w = yv[7];
    float4* ob = (float4*)(out + base);
    ob[0] = y0;
    ob[1] = y1;
}

extern "C" void kernel_launch(void* const* d_in, const int* in_sizes, int n_in,
                              void* d_out, int out_size, void* d_ws, size_t ws_size,
                              hipStream_t stream)
{
    (void)in_sizes; (void)n_in; (void)out_size; (void)ws_size;
    const float* x      = (const float*)d_in[0];
    const float* fe_w   = (const float*)d_in[3];
    const float* fe_b   = (const float*)d_in[4];
    const float* ln_g   = (const float*)d_in[5];
    const float* ln_b   = (const float*)d_in[6];
    const float* w_rel  = (const float*)d_in[7];   // [2][4][128][128]
    const float* w_root = (const float*)d_in[8];   // [2][128][128]
    const float* rgcn_b = (const float*)d_in[9];   // [2][128]
    const float* wq  = (const float*)d_in[10];
    const float* bq  = (const float*)d_in[11];
    const float* wk  = (const float*)d_in[12];
    const float* bk  = (const float*)d_in[13];
    const float* wv  = (const float*)d_in[14];
    const float* bv  = (const float*)d_in[15];
    const float* wsk = (const float*)d_in[16];
    const float* bsk = (const float*)d_in[17];
    const float* bn_g = (const float*)d_in[18];
    const float* bn_b = (const float*)d_in[19];

    float* ws   = (float*)d_ws;
    float* partials = ws;                              // [4][128][256] f32
    unsigned short* out2_bf = (unsigned short*)(partials + 4 * 128 * 256); // [8192][128]
    unsigned short* nf_bf   = out2_bf + (size_t)NODES * G_;
    unsigned short* nf1_bf  = nf_bf + (size_t)NODES * G_;
    unsigned short* wbf     = nf1_bf + (size_t)NODES * G_;  // 16 x [128][128]

    WconvArgs wa;
    for (int l = 0; l < 2; ++l) {
        for (int r = 0; r < 4; ++r) {
            wa.src[l * 8 + r] = w_rel + ((size_t)l * 4 + r) * G_ * G_;
            wa.add[l * 8 + r] = (r == 0) ? (w_root + (size_t)l * G_ * G_) : nullptr;
        }
        wa.src[l * 8 + 4] = wq  + (size_t)l * G_ * G_; wa.add[l * 8 + 4] = nullptr;
        wa.src[l * 8 + 5] = wk  + (size_t)l * G_ * G_; wa.add[l * 8 + 5] = nullptr;
        wa.src[l * 8 + 6] = wv  + (size_t)l * G_ * G_; wa.add[l * 8 + 6] = nullptr;
        wa.src[l * 8 + 7] = wsk + (size_t)l * G_ * G_; wa.add[l * 8 + 7] = nullptr;
    }

    pool_fc_ln_kernel<<<NODES, 192, 0, stream>>>(
        x, fe_w, fe_b, ln_g, ln_b, nf_bf, wa, wbf);

    // ---- layer 0 ----
    rgcn_fused_kernel<false><<<512, 512, 0, stream>>>(
        nf_bf, nullptr, nullptr, nullptr, nullptr,
        wbf, rgcn_b, nf1_bf);
    qkvs_attn_kernel<<<512, 512, 0, stream>>>(
        nf1_bf, wbf + (size_t)4 * 16384,
        bq, bk, bv, bsk, out2_bf, partials);

    // ---- layer 1 (BN of layer-0 folded into rgcn staging) ----
    rgcn_fused_kernel<true><<<512, 512, 0, stream>>>(
        nullptr, out2_bf, partials, bn_g, bn_b,
        wbf + (size_t)8 * 16384, rgcn_b + G_, nf1_bf);
    qkvs_attn_kernel<<<512, 512, 0, stream>>>(
        nf1_bf, wbf + (size_t)12 * 16384,
        bq + G_, bk + G_, bv + G_, bsk + G_, out2_bf, partials);

    bn_apply_kernel<<<512, 256, 0, stream>>>(
        out2_bf, partials, bn_g + G_, bn_b + G_, (float*)d_out);
}